// Round 1
// baseline (7198.157 us; speedup 1.0000x reference)
//
#include <hip/hip_runtime.h>
#include <math.h>

#define DD   72
#define MID  36
#define CTXN 8
#define HIDN 64
#define NBLK 16

// ---------------------------------------------------------------------------
// Kernel 1: precompute per-block W = (tril(lL,-1)+I) @ (triu(lU,1)+diag(d))
// and per-block sum(log(diag)). Batch-independent.
// ---------------------------------------------------------------------------
__global__ __launch_bounds__(256) void precompute_kernel(
    const float* __restrict__ lu_lower,
    const float* __restrict__ lu_upper,
    const float* __restrict__ lu_diag,
    float* __restrict__ wsW,     // [NBLK][DD][DD]
    float* __restrict__ wsLd)    // [NBLK]
{
    const int blk = blockIdx.x;
    const int tid = threadIdx.x;
    __shared__ float diag[DD];
    __shared__ float ldpart[DD];

    if (tid < DD) {
        float v  = lu_diag[blk * DD + tid];
        float sp = log1pf(expf(v)) + 0.001f;   // softplus + eps
        diag[tid]   = sp;
        ldpart[tid] = logf(sp);
    }
    __syncthreads();
    if (tid == 0) {
        float s = 0.f;
        for (int i = 0; i < DD; ++i) s += ldpart[i];
        wsLd[blk] = s;
    }

    const float* L = lu_lower + blk * DD * DD;
    const float* U = lu_upper + blk * DD * DD;
    for (int e = tid; e < DD * DD; e += 256) {
        int i = e / DD, j = e % DD;
        int m = (i < j) ? i : j;
        float s = 0.f;
        for (int k = 0; k <= m; ++k) {
            float a = (k < i) ? L[i * DD + k] : 1.0f;       // unit lower
            float b = (k < j) ? U[k * DD + j] : diag[j];    // upper + diag
            s = fmaf(a, b, s);
        }
        wsW[blk * DD * DD + e] = s;
    }
}

// ---------------------------------------------------------------------------
// Kernel 2: one thread per batch element. All activations in registers,
// fully unrolled; weights are wave-uniform -> scalar loads.
// ---------------------------------------------------------------------------
__global__ __launch_bounds__(256, 1) void flow_kernel(
    const float* __restrict__ traj,
    const float* __restrict__ start,
    const float* __restrict__ goal,
    const float* __restrict__ lu_bias,
    const float* __restrict__ cn_W0,
    const float* __restrict__ cn_b0,
    const float* __restrict__ cn_ctxW,
    const float* __restrict__ cn_ctxb,
    const float* __restrict__ cn_l1W,
    const float* __restrict__ cn_l1b,
    const float* __restrict__ cn_l2W,
    const float* __restrict__ cn_l2b,
    const float* __restrict__ cn_Wf,
    const float* __restrict__ cn_bf,
    const float* __restrict__ enc_W1,
    const float* __restrict__ enc_b1,
    const float* __restrict__ enc_W2,
    const float* __restrict__ enc_b2,
    const float* __restrict__ wsW,
    const float* __restrict__ wsLd,
    float* __restrict__ out,
    int B)
{
    const int b = blockIdx.x * blockDim.x + threadIdx.x;
    if (b >= B) return;

    float x[DD];
    {
        const float4* tp = reinterpret_cast<const float4*>(traj) + (size_t)b * (DD / 4);
        #pragma unroll
        for (int i = 0; i < DD / 4; ++i) {
            float4 v = tp[i];
            x[4 * i + 0] = v.x; x[4 * i + 1] = v.y;
            x[4 * i + 2] = v.z; x[4 * i + 3] = v.w;
        }
    }
    float ctx[CTXN];
    {
        float4 s4 = reinterpret_cast<const float4*>(start)[b];
        float4 g4 = reinterpret_cast<const float4*>(goal)[b];
        ctx[0] = s4.x; ctx[1] = s4.y; ctx[2] = s4.z; ctx[3] = s4.w;
        ctx[4] = g4.x; ctx[5] = g4.y; ctx[6] = g4.z; ctx[7] = g4.w;
    }

    float ld = 0.f;

    #pragma unroll 1
    for (int blk = 0; blk < NBLK; ++blk) {
        const float* W  = wsW     + blk * DD * DD;
        const float* lb = lu_bias + blk * DD;
        const float* W0 = cn_W0   + blk * HIDN * (MID + CTXN);
        const float* b0 = cn_b0   + blk * HIDN;
        const float* Wf = cn_Wf   + blk * DD * HIDN;
        const float* bf = cn_bf   + blk * DD;

        // ---- x @ W.T + lb ----
        float y[DD];
        #pragma unroll
        for (int i = 0; i < DD; ++i) {
            float acc = lb[i];
            #pragma unroll
            for (int j = 0; j < DD; ++j) acc = fmaf(W[i * DD + j], x[j], acc);
            y[i] = acc;
        }
        // x fully dead now; h_id = y[MID..DD)

        // ---- resnet: t = concat(h_id, ctx) @ W0.T + b0 ----
        float t[HIDN];
        #pragma unroll
        for (int j = 0; j < HIDN; ++j) {
            float acc = b0[j];
            #pragma unroll
            for (int m = 0; m < MID; ++m)
                acc = fmaf(W0[j * (MID + CTXN) + m], y[MID + m], acc);
            #pragma unroll
            for (int c = 0; c < CTXN; ++c)
                acc = fmaf(W0[j * (MID + CTXN) + MID + c], ctx[c], acc);
            t[j] = acc;
        }

        #pragma unroll
        for (int i = 0; i < 2; ++i) {
            const float* l1W = cn_l1W  + (blk * 2 + i) * HIDN * HIDN;
            const float* l1b = cn_l1b  + (blk * 2 + i) * HIDN;
            const float* l2W = cn_l2W  + (blk * 2 + i) * HIDN * HIDN;
            const float* l2b = cn_l2b  + (blk * 2 + i) * HIDN;
            const float* cW  = cn_ctxW + (blk * 2 + i) * HIDN * CTXN;
            const float* cb  = cn_ctxb + (blk * 2 + i) * HIDN;

            float rt[HIDN];
            #pragma unroll
            for (int k = 0; k < HIDN; ++k) rt[k] = fmaxf(t[k], 0.f);

            float a[HIDN];
            #pragma unroll
            for (int j = 0; j < HIDN; ++j) {
                float acc = l1b[j];
                #pragma unroll
                for (int k = 0; k < HIDN; ++k)
                    acc = fmaf(l1W[j * HIDN + k], rt[k], acc);
                a[j] = fmaxf(acc, 0.f);   // relu applied for the next matvec
            }
            #pragma unroll
            for (int j = 0; j < HIDN; ++j) {
                float acc = l2b[j];
                #pragma unroll
                for (int k = 0; k < HIDN; ++k)
                    acc = fmaf(l2W[j * HIDN + k], a[k], acc);
                float g = cb[j];
                #pragma unroll
                for (int c = 0; c < CTXN; ++c)
                    g = fmaf(cW[j * CTXN + c], ctx[c], g);
                g = 1.f / (1.f + expf(-g));   // sigmoid gate
                t[j] = fmaf(acc, g, t[j]);    // t += a2 * gate
            }
        }

        // ---- params = t @ Wf.T + bf ; affine coupling ----
        #pragma unroll
        for (int m = 0; m < MID; ++m) {
            float sh = bf[m];
            #pragma unroll
            for (int k = 0; k < HIDN; ++k)
                sh = fmaf(Wf[m * HIDN + k], t[k], sh);
            float sc = bf[MID + m];
            #pragma unroll
            for (int k = 0; k < HIDN; ++k)
                sc = fmaf(Wf[(MID + m) * HIDN + k], t[k], sc);
            sc = 1.f / (1.f + expf(-(sc + 2.f))) + 0.001f;
            x[m] = fmaf(y[m], sc, sh);
            ld += logf(sc);
        }
        #pragma unroll
        for (int m = MID; m < DD; ++m) x[m] = y[m];
    }

    // ---- encoder head ----
    float h[HIDN];
    #pragma unroll
    for (int j = 0; j < HIDN; ++j) {
        float acc = enc_b1[j];
        #pragma unroll
        for (int c = 0; c < CTXN; ++c)
            acc = fmaf(enc_W1[j * CTXN + c], ctx[c], acc);
        h[j] = fmaxf(acc, 0.f);
    }
    float q = 0.f, sls = 0.f;
    #pragma unroll
    for (int i = 0; i < DD; ++i) {
        float mean = enc_b2[i];
        #pragma unroll
        for (int j = 0; j < HIDN; ++j)
            mean = fmaf(enc_W2[i * HIDN + j], h[j], mean);
        float lsd = enc_b2[DD + i];
        #pragma unroll
        for (int j = 0; j < HIDN; ++j)
            lsd = fmaf(enc_W2[(DD + i) * HIDN + j], h[j], lsd);
        float z = (x[i] - mean) * expf(-lsd);
        q = fmaf(z, z, q);
        sls += lsd;
    }

    float ldsum = 0.f;
    #pragma unroll
    for (int k = 0; k < NBLK; ++k) ldsum += wsLd[k];

    // 0.5 * 72 * log(2*pi) = 66.16357439
    out[b] = -0.5f * q - sls - 66.1635744f + ld + ldsum;
}

// ---------------------------------------------------------------------------
extern "C" void kernel_launch(void* const* d_in, const int* in_sizes, int n_in,
                              void* d_out, int out_size, void* d_ws, size_t ws_size,
                              hipStream_t stream) {
    const float* traj     = (const float*)d_in[0];
    const float* start    = (const float*)d_in[1];
    const float* goal     = (const float*)d_in[2];
    const float* lu_lower = (const float*)d_in[3];
    const float* lu_upper = (const float*)d_in[4];
    const float* lu_diag  = (const float*)d_in[5];
    const float* lu_bias  = (const float*)d_in[6];
    const float* cn_W0    = (const float*)d_in[7];
    const float* cn_b0    = (const float*)d_in[8];
    const float* cn_ctxW  = (const float*)d_in[9];
    const float* cn_ctxb  = (const float*)d_in[10];
    const float* cn_l1W   = (const float*)d_in[11];
    const float* cn_l1b   = (const float*)d_in[12];
    const float* cn_l2W   = (const float*)d_in[13];
    const float* cn_l2b   = (const float*)d_in[14];
    const float* cn_Wf    = (const float*)d_in[15];
    const float* cn_bf    = (const float*)d_in[16];
    const float* enc_W1   = (const float*)d_in[17];
    const float* enc_b1   = (const float*)d_in[18];
    const float* enc_W2   = (const float*)d_in[19];
    const float* enc_b2   = (const float*)d_in[20];

    float* outp = (float*)d_out;
    const int B = in_sizes[0] / DD;

    float* wsW  = (float*)d_ws;                 // NBLK*DD*DD floats
    float* wsLd = wsW + NBLK * DD * DD;         // NBLK floats

    hipLaunchKernelGGL(precompute_kernel, dim3(NBLK), dim3(256), 0, stream,
                       lu_lower, lu_upper, lu_diag, wsW, wsLd);

    hipLaunchKernelGGL(flow_kernel, dim3((B + 255) / 256), dim3(256), 0, stream,
                       traj, start, goal, lu_bias,
                       cn_W0, cn_b0, cn_ctxW, cn_ctxb,
                       cn_l1W, cn_l1b, cn_l2W, cn_l2b,
                       cn_Wf, cn_bf,
                       enc_W1, enc_b1, enc_W2, enc_b2,
                       wsW, wsLd, outp, B);
}

// Round 4
// 1846.465 us; speedup vs baseline: 3.8983x; 3.8983x over previous
//
#include <hip/hip_runtime.h>
#include <math.h>

#define DD   72
#define MID  36
#define CTXN 8
#define HIDN 64
#define NBLK 16
#define W0K  44   // MID + CTXN

// ---------------------------------------------------------------------------
// Kernel 1: precompute per-block W = (tril(lL,-1)+I) @ (triu(lU,1)+diag(d))
// and per-block sum(log(diag)). Batch-independent.
// ---------------------------------------------------------------------------
__global__ __launch_bounds__(256) void precompute_kernel(
    const float* __restrict__ lu_lower,
    const float* __restrict__ lu_upper,
    const float* __restrict__ lu_diag,
    float* __restrict__ wsW,     // [NBLK][DD][DD]
    float* __restrict__ wsLd)    // [NBLK]
{
    const int blk = blockIdx.x;
    const int tid = threadIdx.x;
    __shared__ float diag[DD];
    __shared__ float ldpart[DD];

    if (tid < DD) {
        float v  = lu_diag[blk * DD + tid];
        float sp = log1pf(expf(v)) + 0.001f;   // softplus + eps
        diag[tid]   = sp;
        ldpart[tid] = logf(sp);
    }
    __syncthreads();
    if (tid == 0) {
        float s = 0.f;
        for (int i = 0; i < DD; ++i) s += ldpart[i];
        wsLd[blk] = s;
    }

    const float* L = lu_lower + blk * DD * DD;
    const float* U = lu_upper + blk * DD * DD;
    for (int e = tid; e < DD * DD; e += 256) {
        int i = e / DD, j = e % DD;
        int m = (i < j) ? i : j;
        float s = 0.f;
        for (int k = 0; k <= m; ++k) {
            float a = (k < i) ? L[i * DD + k] : 1.0f;       // unit lower
            float b = (k < j) ? U[k * DD + j] : diag[j];    // upper + diag
            s = fmaf(a, b, s);
        }
        wsW[blk * DD * DD + e] = s;
    }
}

// ---------------------------------------------------------------------------
// Kernel 2: cooperative. 256 threads = 4 row-groups x 64 batch-lanes.
// Activations in LDS as [feature][batch] (lane=batch -> conflict-free).
// Weights are wave-uniform -> scalar loads. Per-thread state stays tiny.
// ---------------------------------------------------------------------------
__global__ __launch_bounds__(256, 4) void flow_kernel(
    const float* __restrict__ traj,
    const float* __restrict__ start,
    const float* __restrict__ goal,
    const float* __restrict__ lu_bias,
    const float* __restrict__ cn_W0,
    const float* __restrict__ cn_b0,
    const float* __restrict__ cn_ctxW,
    const float* __restrict__ cn_ctxb,
    const float* __restrict__ cn_l1W,
    const float* __restrict__ cn_l1b,
    const float* __restrict__ cn_l2W,
    const float* __restrict__ cn_l2b,
    const float* __restrict__ cn_Wf,
    const float* __restrict__ cn_bf,
    const float* __restrict__ enc_W1,
    const float* __restrict__ enc_b1,
    const float* __restrict__ enc_W2,
    const float* __restrict__ enc_b2,
    const float* __restrict__ wsW,
    const float* __restrict__ wsLd,
    float* __restrict__ out,
    int B)
{
    __shared__ float Xs[DD][64];    // activation vector (72) x batch
    __shared__ float Ts[HIDN][64];  // hidden (64) x batch, multi-purpose

    const int tid  = threadIdx.x;
    const int lane = tid & 63;
    const int g    = __builtin_amdgcn_readfirstlane(tid >> 6);  // wave-uniform row group
    int bb = blockIdx.x * 64 + lane;
    if (bb >= B) bb = B - 1;   // tail clamp (duplicate work, same value written)

    // ---- per-thread context (8 regs) ----
    float ctx[CTXN];
    {
        float4 s4 = reinterpret_cast<const float4*>(start)[bb];
        float4 g4 = reinterpret_cast<const float4*>(goal)[bb];
        ctx[0] = s4.x; ctx[1] = s4.y; ctx[2] = s4.z; ctx[3] = s4.w;
        ctx[4] = g4.x; ctx[5] = g4.y; ctx[6] = g4.z; ctx[7] = g4.w;
    }

    // ---- load trajectory tile into Xs (transposed) ----
    for (int c = g; c < DD / 4; c += 4) {
        float4 v = *reinterpret_cast<const float4*>(traj + (size_t)bb * DD + 4 * c);
        Xs[4 * c + 0][lane] = v.x; Xs[4 * c + 1][lane] = v.y;
        Xs[4 * c + 2][lane] = v.z; Xs[4 * c + 3][lane] = v.w;
    }

    float ld = 0.f;
    float ylow[9];

    #pragma unroll 1
    for (int blk = 0; blk < NBLK; ++blk) {
        const float* Wm  = wsW     + blk * DD * DD;
        const float* lb  = lu_bias + blk * DD;
        const float* W0  = cn_W0   + blk * HIDN * W0K;
        const float* b0  = cn_b0   + blk * HIDN;
        const float* Wf  = cn_Wf   + blk * DD * HIDN;
        const float* bf  = cn_bf   + blk * DD;

        __syncthreads();   // Xs fully valid

        // ---- step1: y = W @ x + lb.  Thread owns y rows {9g..9g+9} and {36+9g..}
        float acc[18];
        #pragma unroll
        for (int i = 0; i < 9; ++i) acc[i]     = lb[9 * g + i];
        #pragma unroll
        for (int i = 0; i < 9; ++i) acc[9 + i] = lb[MID + 9 * g + i];
        for (int k0 = 0; k0 < DD; k0 += 8) {
            #pragma unroll
            for (int kk = 0; kk < 8; ++kk) {
                const int k = k0 + kk;
                const float xk = Xs[k][lane];
                #pragma unroll
                for (int i = 0; i < 9; ++i)
                    acc[i]     = fmaf(Wm[(9 * g + i) * DD + k],       xk, acc[i]);
                #pragma unroll
                for (int i = 0; i < 9; ++i)
                    acc[9 + i] = fmaf(Wm[(MID + 9 * g + i) * DD + k], xk, acc[9 + i]);
            }
        }
        __syncthreads();   // all Xs reads done
        #pragma unroll
        for (int i = 0; i < 9; ++i) {
            ylow[i] = acc[i];
            Xs[MID + 9 * g + i][lane] = acc[9 + i];   // h_id written in place
        }
        __syncthreads();   // h_id valid

        // ---- step2: t = W0 @ [h_id; ctx] + b0.  Thread owns t rows {16g..16g+16}
        float t[16];
        #pragma unroll
        for (int j = 0; j < 16; ++j) t[j] = b0[16 * g + j];
        for (int k0 = 0; k0 < MID; k0 += 4) {
            #pragma unroll
            for (int kk = 0; kk < 4; ++kk) {
                const int k = k0 + kk;
                const float hk = Xs[MID + k][lane];
                #pragma unroll
                for (int j = 0; j < 16; ++j)
                    t[j] = fmaf(W0[(16 * g + j) * W0K + k], hk, t[j]);
            }
        }
        #pragma unroll
        for (int c = 0; c < CTXN; ++c) {
            #pragma unroll
            for (int j = 0; j < 16; ++j)
                t[j] = fmaf(W0[(16 * g + j) * W0K + MID + c], ctx[c], t[j]);
        }
        #pragma unroll
        for (int j = 0; j < 16; ++j) Ts[16 * g + j][lane] = t[j];  // raw t
        __syncthreads();   // Ts = t valid

        // ---- step3: two residual blocks
        #pragma unroll 1
        for (int i = 0; i < 2; ++i) {
            const float* l1W = cn_l1W  + (blk * 2 + i) * HIDN * HIDN;
            const float* l1b = cn_l1b  + (blk * 2 + i) * HIDN;
            const float* l2W = cn_l2W  + (blk * 2 + i) * HIDN * HIDN;
            const float* l2b = cn_l2b  + (blk * 2 + i) * HIDN;
            const float* cW  = cn_ctxW + (blk * 2 + i) * HIDN * CTXN;
            const float* cb  = cn_ctxb + (blk * 2 + i) * HIDN;

            float a1[16];
            #pragma unroll
            for (int j = 0; j < 16; ++j) a1[j] = l1b[16 * g + j];
            for (int k0 = 0; k0 < HIDN; k0 += 8) {
                #pragma unroll
                for (int kk = 0; kk < 8; ++kk) {
                    const int k = k0 + kk;
                    const float rk = fmaxf(Ts[k][lane], 0.f);   // relu(t) at read
                    #pragma unroll
                    for (int j = 0; j < 16; ++j)
                        a1[j] = fmaf(l1W[(16 * g + j) * HIDN + k], rk, a1[j]);
                }
            }
            __syncthreads();   // Ts(t) reads done
            #pragma unroll
            for (int j = 0; j < 16; ++j) Ts[16 * g + j][lane] = a1[j];  // raw a1
            __syncthreads();   // Ts = a1 valid

            float a2[16];
            #pragma unroll
            for (int j = 0; j < 16; ++j) a2[j] = l2b[16 * g + j];
            for (int k0 = 0; k0 < HIDN; k0 += 8) {
                #pragma unroll
                for (int kk = 0; kk < 8; ++kk) {
                    const int k = k0 + kk;
                    const float rk = fmaxf(Ts[k][lane], 0.f);   // relu(a1) at read
                    #pragma unroll
                    for (int j = 0; j < 16; ++j)
                        a2[j] = fmaf(l2W[(16 * g + j) * HIDN + k], rk, a2[j]);
                }
            }
            #pragma unroll
            for (int j = 0; j < 16; ++j) {
                float gg = cb[16 * g + j];
                #pragma unroll
                for (int c = 0; c < CTXN; ++c)
                    gg = fmaf(cW[(16 * g + j) * CTXN + c], ctx[c], gg);
                gg = 1.f / (1.f + expf(-gg));
                t[j] = fmaf(a2[j], gg, t[j]);
            }
            __syncthreads();   // Ts(a1) reads done
            #pragma unroll
            for (int j = 0; j < 16; ++j) Ts[16 * g + j][lane] = t[j];  // raw new t
            __syncthreads();   // Ts = t valid
        }

        // ---- step4: params rows; thread owns shift {9g..9g+9}, scale {36+9g..}
        float sh[9], sc[9];
        #pragma unroll
        for (int m = 0; m < 9; ++m) { sh[m] = bf[9 * g + m]; sc[m] = bf[MID + 9 * g + m]; }
        for (int k0 = 0; k0 < HIDN; k0 += 8) {
            #pragma unroll
            for (int kk = 0; kk < 8; ++kk) {
                const int k = k0 + kk;
                const float tk = Ts[k][lane];
                #pragma unroll
                for (int m = 0; m < 9; ++m)
                    sh[m] = fmaf(Wf[(9 * g + m) * HIDN + k],       tk, sh[m]);
                #pragma unroll
                for (int m = 0; m < 9; ++m)
                    sc[m] = fmaf(Wf[(MID + 9 * g + m) * HIDN + k], tk, sc[m]);
            }
        }
        // ---- combine: x_new[m] = y[m]*scale + shift (in regs), write Xs lows
        #pragma unroll
        for (int m = 0; m < 9; ++m) {
            float s = 1.f / (1.f + expf(-(sc[m] + 2.f))) + 0.001f;
            Xs[9 * g + m][lane] = fmaf(ylow[m], s, sh[m]);
            ld += logf(s);
        }
        // loop-top barrier protects Xs/Ts reuse
    }

    // ---- encoder head ----
    __syncthreads();   // final combine writes visible; Ts free
    #pragma unroll
    for (int j = 0; j < 16; ++j) {
        float acc = enc_b1[16 * g + j];
        #pragma unroll
        for (int c = 0; c < CTXN; ++c)
            acc = fmaf(enc_W1[(16 * g + j) * CTXN + c], ctx[c], acc);
        Ts[16 * g + j][lane] = acc;   // raw h, relu at read
    }
    __syncthreads();

    // means/log_std are each DD=72 wide: thread group owns 18 rows of each.
    float mean[18], lsd[18];
    #pragma unroll
    for (int m = 0; m < 18; ++m) {
        mean[m] = enc_b2[18 * g + m];
        lsd[m]  = enc_b2[DD + 18 * g + m];
    }
    for (int k0 = 0; k0 < HIDN; k0 += 8) {
        #pragma unroll
        for (int kk = 0; kk < 8; ++kk) {
            const int k = k0 + kk;
            const float hk = fmaxf(Ts[k][lane], 0.f);
            #pragma unroll
            for (int m = 0; m < 18; ++m)
                mean[m] = fmaf(enc_W2[(18 * g + m) * HIDN + k],      hk, mean[m]);
            #pragma unroll
            for (int m = 0; m < 18; ++m)
                lsd[m]  = fmaf(enc_W2[(DD + 18 * g + m) * HIDN + k], hk, lsd[m]);
        }
    }
    float q = 0.f, sls = 0.f;
    #pragma unroll
    for (int m = 0; m < 18; ++m) {
        const float z = (Xs[18 * g + m][lane] - mean[m]) * expf(-lsd[m]);
        q = fmaf(z, z, q);
        sls += lsd[m];
    }

    __syncthreads();   // Ts(h) reads done
    Ts[g][lane]     = q;
    Ts[4 + g][lane] = sls;
    Ts[8 + g][lane] = ld;
    __syncthreads();
    if (g == 0) {
        float qt = 0.f, st = 0.f, lt = 0.f;
        #pragma unroll
        for (int k = 0; k < 4; ++k) {
            qt += Ts[k][lane]; st += Ts[4 + k][lane]; lt += Ts[8 + k][lane];
        }
        float ldsum = 0.f;
        #pragma unroll
        for (int k = 0; k < NBLK; ++k) ldsum += wsLd[k];
        // 0.5 * 72 * log(2*pi) = 66.16357439
        out[bb] = -0.5f * qt - st - 66.1635744f + lt + ldsum;
    }
}

// ---------------------------------------------------------------------------
extern "C" void kernel_launch(void* const* d_in, const int* in_sizes, int n_in,
                              void* d_out, int out_size, void* d_ws, size_t ws_size,
                              hipStream_t stream) {
    const float* traj     = (const float*)d_in[0];
    const float* start    = (const float*)d_in[1];
    const float* goal     = (const float*)d_in[2];
    const float* lu_lower = (const float*)d_in[3];
    const float* lu_upper = (const float*)d_in[4];
    const float* lu_diag  = (const float*)d_in[5];
    const float* lu_bias  = (const float*)d_in[6];
    const float* cn_W0    = (const float*)d_in[7];
    const float* cn_b0    = (const float*)d_in[8];
    const float* cn_ctxW  = (const float*)d_in[9];
    const float* cn_ctxb  = (const float*)d_in[10];
    const float* cn_l1W   = (const float*)d_in[11];
    const float* cn_l1b   = (const float*)d_in[12];
    const float* cn_l2W   = (const float*)d_in[13];
    const float* cn_l2b   = (const float*)d_in[14];
    const float* cn_Wf    = (const float*)d_in[15];
    const float* cn_bf    = (const float*)d_in[16];
    const float* enc_W1   = (const float*)d_in[17];
    const float* enc_b1   = (const float*)d_in[18];
    const float* enc_W2   = (const float*)d_in[19];
    const float* enc_b2   = (const float*)d_in[20];

    float* outp = (float*)d_out;
    const int B = in_sizes[0] / DD;

    float* wsW  = (float*)d_ws;                 // NBLK*DD*DD floats
    float* wsLd = wsW + NBLK * DD * DD;         // NBLK floats

    hipLaunchKernelGGL(precompute_kernel, dim3(NBLK), dim3(256), 0, stream,
                       lu_lower, lu_upper, lu_diag, wsW, wsLd);

    const int ngrp = (B + 63) / 64;
    hipLaunchKernelGGL(flow_kernel, dim3(ngrp), dim3(256), 0, stream,
                       traj, start, goal, lu_bias,
                       cn_W0, cn_b0, cn_ctxW, cn_ctxb,
                       cn_l1W, cn_l1b, cn_l2W, cn_l2b,
                       cn_Wf, cn_bf,
                       enc_W1, enc_b1, enc_W2, enc_b2,
                       wsW, wsLd, outp, B);
}

// Round 5
// 1165.071 us; speedup vs baseline: 6.1783x; 1.5849x over previous
//
#include <hip/hip_runtime.h>
#include <math.h>

#define DD   72
#define MID  36
#define CTXN 8
#define HIDN 64
#define NBLK 16
#define W0K  44   // MID + CTXN

// ---- packed f16 helpers -----------------------------------------------------
typedef _Float16 h2 __attribute__((ext_vector_type(2)));
union HU { unsigned u; h2 h; _Float16 s[2]; };

__device__ inline float dot2(unsigned w, unsigned x, float c) {
#if __has_builtin(__builtin_amdgcn_fdot2)
    HU uw, ux; uw.u = w; ux.u = x;
    return __builtin_amdgcn_fdot2(uw.h, ux.h, c, false);
#else
    HU uw, ux; uw.u = w; ux.u = x;
    return fmaf((float)uw.s[1], (float)ux.s[1],
                fmaf((float)uw.s[0], (float)ux.s[0], c));
#endif
}
__device__ inline unsigned pk(float a, float b) {
    HU u; u.s[0] = (_Float16)a; u.s[1] = (_Float16)b; return u.u;
}
__device__ inline unsigned relu2(unsigned x) {
    HU u; u.u = x;
    u.s[0] = u.s[0] > (_Float16)0.f ? u.s[0] : (_Float16)0.f;
    u.s[1] = u.s[1] > (_Float16)0.f ? u.s[1] : (_Float16)0.f;
    return u.u;
}
__device__ inline void st_half(unsigned (*buf)[64], int row, int lane, float v) {
    _Float16* p = (_Float16*)buf;
    p[((row >> 1) * 64 + lane) * 2 + (row & 1)] = (_Float16)v;
}
__device__ inline float ld_half(const unsigned (*buf)[64], int row, int lane) {
    const _Float16* p = (const _Float16*)buf;
    return (float)p[((row >> 1) * 64 + lane) * 2 + (row & 1)];
}

// cn16 segment offsets (uint32 pair units)
#define OFF_W0   0
#define OFF_CW   22528
#define OFF_L1   30720
#define OFF_L2   96256
#define OFF_WF   161792
#define OFF_EW1  198656
#define OFF_EW2  198912
#define CN16_TOTAL 203520

// ---------------------------------------------------------------------------
// Kernel 1: per-block W = (tril(lL,-1)+I)@(triu(lU,1)+diag(softplus+eps)),
// written directly as packed f16 pairs; plus sum(log(diag)).
// ---------------------------------------------------------------------------
__global__ __launch_bounds__(256) void precompute_kernel(
    const float* __restrict__ lu_lower,
    const float* __restrict__ lu_upper,
    const float* __restrict__ lu_diag,
    unsigned* __restrict__ wm16,   // [NBLK][72][36] u32 pairs
    float* __restrict__ wsLd)      // [NBLK]
{
    const int blk = blockIdx.x;
    const int tid = threadIdx.x;
    __shared__ float diag[DD];
    __shared__ float ldpart[DD];

    if (tid < DD) {
        float v  = lu_diag[blk * DD + tid];
        float sp = log1pf(expf(v)) + 0.001f;
        diag[tid]   = sp;
        ldpart[tid] = logf(sp);
    }
    __syncthreads();
    if (tid == 0) {
        float s = 0.f;
        for (int i = 0; i < DD; ++i) s += ldpart[i];
        wsLd[blk] = s;
    }

    const float* L = lu_lower + blk * DD * DD;
    const float* U = lu_upper + blk * DD * DD;
    for (int p = tid; p < DD * DD / 2; p += 256) {
        int e0 = 2 * p;
        int i = e0 / DD, j0 = e0 % DD;          // j0 even; j0+1 in same row
        int m0 = (i < j0) ? i : j0;
        int m1 = (i < j0 + 1) ? i : j0 + 1;
        float s0 = 0.f, s1 = 0.f;
        for (int k = 0; k <= m1; ++k) {
            float a = (k < i) ? L[i * DD + k] : 1.0f;
            if (k <= m0) {
                float b0 = (k < j0) ? U[k * DD + j0] : diag[j0];
                s0 = fmaf(a, b0, s0);
            }
            float b1 = (k < j0 + 1) ? U[k * DD + j0 + 1] : diag[j0 + 1];
            s1 = fmaf(a, b1, s1);
        }
        wm16[blk * 2592 + i * 36 + (j0 >> 1)] = pk(s0, s1);
    }
}

// ---------------------------------------------------------------------------
// Kernel 1b: convert static weights to packed f16 (flat pairing is valid
// because every matrix row length is even).
// ---------------------------------------------------------------------------
__global__ __launch_bounds__(256) void convert_kernel(
    const float* __restrict__ cn_W0, const float* __restrict__ cn_ctxW,
    const float* __restrict__ cn_l1W, const float* __restrict__ cn_l2W,
    const float* __restrict__ cn_Wf, const float* __restrict__ enc_W1,
    const float* __restrict__ enc_W2, unsigned* __restrict__ dst)
{
    int idx = blockIdx.x * blockDim.x + threadIdx.x;
    if (idx >= CN16_TOTAL) return;
    const float* src; int off;
    if      (idx < OFF_CW)  { src = cn_W0;   off = idx - OFF_W0;  }
    else if (idx < OFF_L1)  { src = cn_ctxW; off = idx - OFF_CW;  }
    else if (idx < OFF_L2)  { src = cn_l1W;  off = idx - OFF_L1;  }
    else if (idx < OFF_WF)  { src = cn_l2W;  off = idx - OFF_L2;  }
    else if (idx < OFF_EW1) { src = cn_Wf;   off = idx - OFF_WF;  }
    else if (idx < OFF_EW2) { src = enc_W1;  off = idx - OFF_EW1; }
    else                    { src = enc_W2;  off = idx - OFF_EW2; }
    float2 v = reinterpret_cast<const float2*>(src)[off];
    dst[idx] = pk(v.x, v.y);
}

// ---------------------------------------------------------------------------
// Kernel 2: cooperative f16-dot2 flow. 256 threads = 4 row-groups x 64 lanes.
// ---------------------------------------------------------------------------
__global__ __launch_bounds__(256, 4) void flow_kernel(
    const float* __restrict__ traj,
    const float* __restrict__ start,
    const float* __restrict__ goal,
    const float* __restrict__ lu_bias,
    const float* __restrict__ cn_b0,
    const float* __restrict__ cn_ctxb,
    const float* __restrict__ cn_l1b,
    const float* __restrict__ cn_l2b,
    const float* __restrict__ cn_bf,
    const float* __restrict__ enc_b1,
    const float* __restrict__ enc_b2,
    const unsigned* __restrict__ wm16,
    const unsigned* __restrict__ cn16,
    const float* __restrict__ wsLd,
    float* __restrict__ out,
    int B)
{
    __shared__ unsigned Xs2[36][64];   // features 0..71 as f16 pairs
    __shared__ unsigned Ts2[32][64];   // hidden 0..63 as f16 pairs
    __shared__ float Red[12][64];

    const int tid  = threadIdx.x;
    const int lane = tid & 63;
    const int g    = __builtin_amdgcn_readfirstlane(tid >> 6);
    int bb = blockIdx.x * 64 + lane;
    if (bb >= B) bb = B - 1;

    unsigned ctx2[4];
    {
        float4 s4 = reinterpret_cast<const float4*>(start)[bb];
        float4 g4 = reinterpret_cast<const float4*>(goal)[bb];
        ctx2[0] = pk(s4.x, s4.y); ctx2[1] = pk(s4.z, s4.w);
        ctx2[2] = pk(g4.x, g4.y); ctx2[3] = pk(g4.z, g4.w);
    }

    for (int c = g; c < DD / 4; c += 4) {
        float4 v = *reinterpret_cast<const float4*>(traj + (size_t)bb * DD + 4 * c);
        Xs2[2 * c][lane]     = pk(v.x, v.y);
        Xs2[2 * c + 1][lane] = pk(v.z, v.w);
    }

    float ld = 0.f;
    float ylow[9];

    #pragma unroll 1
    for (int blk = 0; blk < NBLK; ++blk) {
        const unsigned* Wm = wm16 + blk * 2592;            // [72][36]
        const unsigned* W0 = cn16 + OFF_W0 + blk * 1408;   // [64][22]
        const unsigned* Wf = cn16 + OFF_WF + blk * 2304;   // [72][32]
        const float* lb = lu_bias + blk * DD;
        const float* b0 = cn_b0   + blk * HIDN;
        const float* bf = cn_bf   + blk * DD;

        __syncthreads();   // Xs2 fully valid

        // ---- step1: y = W @ x + lb; rows {9g..9g+8} and {36+9g..36+9g+8}
        float acc[18];
        #pragma unroll
        for (int i = 0; i < 9; ++i) acc[i]     = lb[9 * g + i];
        #pragma unroll
        for (int i = 0; i < 9; ++i) acc[9 + i] = lb[MID + 9 * g + i];
        for (int kp0 = 0; kp0 < 36; kp0 += 6) {
            #pragma unroll
            for (int kk = 0; kk < 6; ++kk) {
                const int kp = kp0 + kk;
                const unsigned x2 = Xs2[kp][lane];
                #pragma unroll
                for (int i = 0; i < 9; ++i)
                    acc[i]     = dot2(Wm[(9 * g + i) * 36 + kp],       x2, acc[i]);
                #pragma unroll
                for (int i = 0; i < 9; ++i)
                    acc[9 + i] = dot2(Wm[(MID + 9 * g + i) * 36 + kp], x2, acc[9 + i]);
            }
        }
        __syncthreads();   // all Xs2 reads done
        #pragma unroll
        for (int i = 0; i < 9; ++i) {
            ylow[i] = acc[i];
            st_half(Xs2, MID + 9 * g + i, lane, acc[9 + i]);  // h_id in place
        }
        __syncthreads();   // h_id valid

        // ---- step2: t = W0 @ [h_id; ctx] + b0; rows {16g..16g+15}
        float t[16];
        #pragma unroll
        for (int j = 0; j < 16; ++j) t[j] = b0[16 * g + j];
        for (int kp0 = 0; kp0 < 18; kp0 += 6) {
            #pragma unroll
            for (int kk = 0; kk < 6; ++kk) {
                const int kp = kp0 + kk;
                const unsigned hv = Xs2[18 + kp][lane];
                #pragma unroll
                for (int j = 0; j < 16; ++j)
                    t[j] = dot2(W0[(16 * g + j) * 22 + kp], hv, t[j]);
            }
        }
        #pragma unroll
        for (int cp = 0; cp < 4; ++cp) {
            #pragma unroll
            for (int j = 0; j < 16; ++j)
                t[j] = dot2(W0[(16 * g + j) * 22 + 18 + cp], ctx2[cp], t[j]);
        }
        #pragma unroll
        for (int qq = 0; qq < 8; ++qq)
            Ts2[8 * g + qq][lane] = pk(t[2 * qq], t[2 * qq + 1]);
        __syncthreads();   // Ts2 = t valid

        // ---- step3: two residual blocks
        #pragma unroll 1
        for (int i = 0; i < 2; ++i) {
            const unsigned* l1W = cn16 + OFF_L1 + (blk * 2 + i) * 2048;  // [64][32]
            const unsigned* l2W = cn16 + OFF_L2 + (blk * 2 + i) * 2048;
            const unsigned* cW  = cn16 + OFF_CW + (blk * 2 + i) * 256;   // [64][4]
            const float* l1b = cn_l1b  + (blk * 2 + i) * HIDN;
            const float* l2b = cn_l2b  + (blk * 2 + i) * HIDN;
            const float* cb  = cn_ctxb + (blk * 2 + i) * HIDN;

            float a1[16];
            #pragma unroll
            for (int j = 0; j < 16; ++j) a1[j] = l1b[16 * g + j];
            for (int kp0 = 0; kp0 < 32; kp0 += 8) {
                #pragma unroll
                for (int kk = 0; kk < 8; ++kk) {
                    const int kp = kp0 + kk;
                    const unsigned rt = relu2(Ts2[kp][lane]);
                    #pragma unroll
                    for (int j = 0; j < 16; ++j)
                        a1[j] = dot2(l1W[(16 * g + j) * 32 + kp], rt, a1[j]);
                }
            }
            __syncthreads();   // Ts2(t) reads done
            #pragma unroll
            for (int qq = 0; qq < 8; ++qq)
                Ts2[8 * g + qq][lane] = pk(a1[2 * qq], a1[2 * qq + 1]);
            __syncthreads();   // Ts2 = a1 valid

            float a2[16];
            #pragma unroll
            for (int j = 0; j < 16; ++j) a2[j] = l2b[16 * g + j];
            for (int kp0 = 0; kp0 < 32; kp0 += 8) {
                #pragma unroll
                for (int kk = 0; kk < 8; ++kk) {
                    const int kp = kp0 + kk;
                    const unsigned rt = relu2(Ts2[kp][lane]);
                    #pragma unroll
                    for (int j = 0; j < 16; ++j)
                        a2[j] = dot2(l2W[(16 * g + j) * 32 + kp], rt, a2[j]);
                }
            }
            #pragma unroll
            for (int j = 0; j < 16; ++j) {
                float gg = cb[16 * g + j];
                #pragma unroll
                for (int cp = 0; cp < 4; ++cp)
                    gg = dot2(cW[(16 * g + j) * 4 + cp], ctx2[cp], gg);
                gg = 1.f / (1.f + expf(-gg));
                t[j] = fmaf(a2[j], gg, t[j]);
            }
            __syncthreads();   // Ts2(a1) reads done
            #pragma unroll
            for (int qq = 0; qq < 8; ++qq)
                Ts2[8 * g + qq][lane] = pk(t[2 * qq], t[2 * qq + 1]);
            __syncthreads();   // Ts2 = t valid
        }

        // ---- step4: shift rows {9g..9g+8}, scale rows {36+9g..36+9g+8}
        float sh[9], sc[9];
        #pragma unroll
        for (int m = 0; m < 9; ++m) { sh[m] = bf[9 * g + m]; sc[m] = bf[MID + 9 * g + m]; }
        for (int kp0 = 0; kp0 < 32; kp0 += 8) {
            #pragma unroll
            for (int kk = 0; kk < 8; ++kk) {
                const int kp = kp0 + kk;
                const unsigned t2 = Ts2[kp][lane];
                #pragma unroll
                for (int m = 0; m < 9; ++m)
                    sh[m] = dot2(Wf[(9 * g + m) * 32 + kp],       t2, sh[m]);
                #pragma unroll
                for (int m = 0; m < 9; ++m)
                    sc[m] = dot2(Wf[(MID + 9 * g + m) * 32 + kp], t2, sc[m]);
            }
        }
        #pragma unroll
        for (int m = 0; m < 9; ++m) {
            float s = 1.f / (1.f + expf(-(sc[m] + 2.f))) + 0.001f;
            st_half(Xs2, 9 * g + m, lane, fmaf(ylow[m], s, sh[m]));
            ld += logf(s);
        }
        // loop-top barrier protects Xs2/Ts2 reuse
    }

    // ---- encoder head ----
    __syncthreads();   // final combine visible; Ts2 free
    {
        float hh[16];
        #pragma unroll
        for (int j = 0; j < 16; ++j) {
            float acc = enc_b1[16 * g + j];
            #pragma unroll
            for (int cp = 0; cp < 4; ++cp)
                acc = dot2(cn16[OFF_EW1 + (16 * g + j) * 4 + cp], ctx2[cp], acc);
            hh[j] = acc;   // raw; relu applied at read
        }
        #pragma unroll
        for (int qq = 0; qq < 8; ++qq)
            Ts2[8 * g + qq][lane] = pk(hh[2 * qq], hh[2 * qq + 1]);
    }
    __syncthreads();

    // means/log_std are each 72 wide: group owns 18 rows of each.
    float mean[18], lsd[18];
    #pragma unroll
    for (int m = 0; m < 18; ++m) {
        mean[m] = enc_b2[18 * g + m];
        lsd[m]  = enc_b2[DD + 18 * g + m];
    }
    for (int kp0 = 0; kp0 < 32; kp0 += 8) {
        #pragma unroll
        for (int kk = 0; kk < 8; ++kk) {
            const int kp = kp0 + kk;
            const unsigned hv = relu2(Ts2[kp][lane]);
            #pragma unroll
            for (int m = 0; m < 18; ++m)
                mean[m] = dot2(cn16[OFF_EW2 + (18 * g + m) * 32 + kp],      hv, mean[m]);
            #pragma unroll
            for (int m = 0; m < 18; ++m)
                lsd[m]  = dot2(cn16[OFF_EW2 + (DD + 18 * g + m) * 32 + kp], hv, lsd[m]);
        }
    }
    float q = 0.f, sls = 0.f;
    #pragma unroll
    for (int m = 0; m < 18; ++m) {
        const float z = (ld_half(Xs2, 18 * g + m, lane) - mean[m]) * expf(-lsd[m]);
        q = fmaf(z, z, q);
        sls += lsd[m];
    }

    Red[g][lane]     = q;
    Red[4 + g][lane] = sls;
    Red[8 + g][lane] = ld;
    __syncthreads();
    if (g == 0) {
        float qt = 0.f, st = 0.f, lt = 0.f;
        #pragma unroll
        for (int k = 0; k < 4; ++k) {
            qt += Red[k][lane]; st += Red[4 + k][lane]; lt += Red[8 + k][lane];
        }
        float ldsum = 0.f;
        #pragma unroll
        for (int k = 0; k < NBLK; ++k) ldsum += wsLd[k];
        // 0.5 * 72 * log(2*pi) = 66.16357439
        out[bb] = -0.5f * qt - st - 66.1635744f + lt + ldsum;
    }
}

// ---------------------------------------------------------------------------
extern "C" void kernel_launch(void* const* d_in, const int* in_sizes, int n_in,
                              void* d_out, int out_size, void* d_ws, size_t ws_size,
                              hipStream_t stream) {
    const float* traj     = (const float*)d_in[0];
    const float* start    = (const float*)d_in[1];
    const float* goal     = (const float*)d_in[2];
    const float* lu_lower = (const float*)d_in[3];
    const float* lu_upper = (const float*)d_in[4];
    const float* lu_diag  = (const float*)d_in[5];
    const float* lu_bias  = (const float*)d_in[6];
    const float* cn_W0    = (const float*)d_in[7];
    const float* cn_b0    = (const float*)d_in[8];
    const float* cn_ctxW  = (const float*)d_in[9];
    const float* cn_ctxb  = (const float*)d_in[10];
    const float* cn_l1W   = (const float*)d_in[11];
    const float* cn_l1b   = (const float*)d_in[12];
    const float* cn_l2W   = (const float*)d_in[13];
    const float* cn_l2b   = (const float*)d_in[14];
    const float* cn_Wf    = (const float*)d_in[15];
    const float* cn_bf    = (const float*)d_in[16];
    const float* enc_W1   = (const float*)d_in[17];
    const float* enc_b1   = (const float*)d_in[18];
    const float* enc_W2   = (const float*)d_in[19];
    const float* enc_b2   = (const float*)d_in[20];

    float* outp = (float*)d_out;
    const int B = in_sizes[0] / DD;

    float*    wsLd = (float*)d_ws;                    // 16 floats (padded to 64 u32)
    unsigned* wm16 = (unsigned*)d_ws + 64;            // 16*2592 u32
    unsigned* cn16 = wm16 + NBLK * 2592;              // CN16_TOTAL u32

    hipLaunchKernelGGL(precompute_kernel, dim3(NBLK), dim3(256), 0, stream,
                       lu_lower, lu_upper, lu_diag, wm16, wsLd);
    hipLaunchKernelGGL(convert_kernel, dim3((CN16_TOTAL + 255) / 256), dim3(256), 0, stream,
                       cn_W0, cn_ctxW, cn_l1W, cn_l2W, cn_Wf, enc_W1, enc_W2, cn16);

    const int ngrp = (B + 63) / 64;
    hipLaunchKernelGGL(flow_kernel, dim3(ngrp), dim3(256), 0, stream,
                       traj, start, goal, lu_bias,
                       cn_b0, cn_ctxb, cn_l1b, cn_l2b, cn_bf,
                       enc_b1, enc_b2, wm16, cn16, wsLd, outp, B);
}

// Round 6
// 598.795 us; speedup vs baseline: 12.0211x; 1.9457x over previous
//
#include <hip/hip_runtime.h>
#include <math.h>

#define DD   72
#define MID  36
#define NBLK 16

typedef _Float16 half8 __attribute__((ext_vector_type(8)));
typedef _Float16 half4 __attribute__((ext_vector_type(4)));
typedef float    f32x4 __attribute__((ext_vector_type(4)));

// ---- A-fragment arena layout (f16 units). Each frag = 64 lanes x 8 f16 = 512.
#define PB    37376            // per-block total
#define S1O   0                // step1 LU matmul: 5 mtiles x 3 ktiles = 15 frags
#define S2O   7680             // step2 W0: 4 x 2 = 8 frags
#define RBO   11776            // resblocks: per i (0/1) stride 10240
#define RB_L1 0                //   l1: 8 frags
#define RB_L2 4096             //   l2: 8 frags
#define RB_GW 8192             //   gate: 4 frags (ktile1 only)
#define S4O   32256            // step4 Wf: 5 x 2 = 10 frags
#define E1O   (16 * PB)        // enc W1: 4 frags
#define E2O   (E1O + 2048)     // enc W2: 9 x 2 = 18 frags
#define AR_TOTAL (E2O + 18 * 512)   // 609280 f16 = 1218560 B

__device__ inline half4 pk4(f32x4 v) {
    half4 h; h[0] = (_Float16)v[0]; h[1] = (_Float16)v[1];
    h[2] = (_Float16)v[2]; h[3] = (_Float16)v[3]; return h;
}
__device__ inline half4 pk4r(f32x4 v) {   // relu + pack
    half4 h;
    h[0] = (_Float16)fmaxf(v[0], 0.f); h[1] = (_Float16)fmaxf(v[1], 0.f);
    h[2] = (_Float16)fmaxf(v[2], 0.f); h[3] = (_Float16)fmaxf(v[3], 0.f);
    return h;
}

// ---------------------------------------------------------------------------
// Prep 1: LU-composed W -> step1 A-frags (f16, fragment-linear) + sum(log diag)
// ---------------------------------------------------------------------------
__global__ __launch_bounds__(256) void prep_lu(
    const float* __restrict__ lu_lower,
    const float* __restrict__ lu_upper,
    const float* __restrict__ lu_diag,
    _Float16* __restrict__ AR, float* __restrict__ wsLd)
{
    const int blk = blockIdx.x, tid = threadIdx.x;
    __shared__ float diag[DD], ldp[DD];
    if (tid < DD) {
        float v  = lu_diag[blk * DD + tid];
        float sp = log1pf(expf(v)) + 0.001f;
        diag[tid] = sp; ldp[tid] = logf(sp);
    }
    __syncthreads();
    if (tid == 0) { float s = 0.f; for (int i = 0; i < DD; ++i) s += ldp[i]; wsLd[blk] = s; }

    const float* L = lu_lower + blk * DD * DD;
    const float* U = lu_upper + blk * DD * DD;
    for (int s = tid; s < 15 * 64; s += 256) {
        int frag = s >> 6, lane = s & 63;
        int mt = frag / 3, kt = frag % 3;
        int m  = mt * 16 + (lane & 15);
        int k0 = kt * 32 + (lane >> 4) * 8;
        half8 hv;
        #pragma unroll
        for (int j = 0; j < 8; ++j) {
            int k = k0 + j;
            float v = 0.f;
            if (m < DD && k < DD) {
                int mm = m < k ? m : k;
                for (int kk = 0; kk <= mm; ++kk) {
                    float a = (kk < m) ? L[m * DD + kk] : 1.0f;
                    float b = (kk < k) ? U[kk * DD + k] : diag[k];
                    v = fmaf(a, b, v);
                }
            }
            hv[j] = (_Float16)v;
        }
        *(half8*)(AR + (size_t)blk * PB + S1O + (size_t)frag * 512 + (size_t)lane * 8) = hv;
    }
}

// ---------------------------------------------------------------------------
// Prep 2: all static weights -> A-frags (950 frags x 64 lanes)
// ---------------------------------------------------------------------------
__global__ __launch_bounds__(256) void prep_w(
    const float* __restrict__ cn_W0, const float* __restrict__ cn_ctxW,
    const float* __restrict__ cn_l1W, const float* __restrict__ cn_l2W,
    const float* __restrict__ cn_Wf, const float* __restrict__ enc_W1,
    const float* __restrict__ enc_W2, _Float16* __restrict__ AR)
{
    int gid = blockIdx.x * 256 + threadIdx.x;
    int fid = gid >> 6, lane = gid & 63;
    if (fid >= 950) return;
    const int mrow = lane & 15, kcol0 = (lane >> 4) * 8;

    const float* src = nullptr; size_t dst = 0;
    int m = 0, kbase = 0, rows = 64, kv_lo = 0, kv_hi = 64, sstr = 64, ksub = 0;

    if (fid < 128) {                    // step2 W0 [64 x 44] over ActH k
        int blk = fid >> 3, f = fid & 7;
        int mt = f >> 1, kt = f & 1;
        src = cn_W0 + (size_t)blk * 64 * 44; sstr = 44;
        dst = (size_t)blk * PB + S2O + (size_t)f * 512;
        m = mt * 16 + mrow; kbase = kt * 32 + kcol0; kv_hi = 44;
    } else if (fid < 384) {             // l1 [64 x 64]
        int id = fid - 128, bi = id >> 3, f = id & 7;
        int mt = f >> 1, kt = f & 1;
        src = cn_l1W + (size_t)bi * 4096;
        dst = (size_t)(bi >> 1) * PB + RBO + (size_t)(bi & 1) * 10240 + RB_L1 + (size_t)f * 512;
        m = mt * 16 + mrow; kbase = kt * 32 + kcol0;
    } else if (fid < 640) {             // l2 [64 x 64]
        int id = fid - 384, bi = id >> 3, f = id & 7;
        int mt = f >> 1, kt = f & 1;
        src = cn_l2W + (size_t)bi * 4096;
        dst = (size_t)(bi >> 1) * PB + RBO + (size_t)(bi & 1) * 10240 + RB_L2 + (size_t)f * 512;
        m = mt * 16 + mrow; kbase = kt * 32 + kcol0;
    } else if (fid < 768) {             // gate cW [64 x 8] at ActH k 36..43, ktile1
        int id = fid - 640, bi = id >> 2, mt = id & 3;
        src = cn_ctxW + (size_t)bi * 512; sstr = 8;
        dst = (size_t)(bi >> 1) * PB + RBO + (size_t)(bi & 1) * 10240 + RB_GW + (size_t)mt * 512;
        m = mt * 16 + mrow; kbase = 32 + kcol0; kv_lo = 36; kv_hi = 44; ksub = 36;
    } else if (fid < 928) {             // step4 Wf [72 x 64]
        int id = fid - 768, blk = id / 10, f = id % 10;
        int mt = f >> 1, kt = f & 1;
        src = cn_Wf + (size_t)blk * 4608;
        dst = (size_t)blk * PB + S4O + (size_t)f * 512;
        m = mt * 16 + mrow; kbase = kt * 32 + kcol0; rows = 72;
    } else if (fid < 932) {             // enc W1 [64 x 8] at ActH k 36..43
        int mt = fid - 928;
        src = enc_W1; sstr = 8;
        dst = E1O + (size_t)mt * 512;
        m = mt * 16 + mrow; kbase = 32 + kcol0; kv_lo = 36; kv_hi = 44; ksub = 36;
    } else {                            // enc W2 [144 x 64]
        int id = fid - 932, mt = id >> 1, kt = id & 1;
        src = enc_W2;
        dst = E2O + (size_t)id * 512;
        m = mt * 16 + mrow; kbase = kt * 32 + kcol0; rows = 144;
    }
    half8 hv;
    #pragma unroll
    for (int j = 0; j < 8; ++j) {
        int k = kbase + j;
        float v = 0.f;
        if (m < rows && k >= kv_lo && k < kv_hi)
            v = src[(size_t)m * sstr + (k - ksub)];
        hv[j] = (_Float16)v;
    }
    *(half8*)(AR + dst + (size_t)lane * 8) = hv;
}

// ---------------------------------------------------------------------------
// Flow kernel: 4 waves/wg, each wave owns 16 batch rows. MFMA 16x16x32 f16.
// Act* LDS buffers are batch-row-partitioned per wave -> no inner barriers.
// ---------------------------------------------------------------------------
#define MFMA_A(acc, off, bf) \
    acc = __builtin_amdgcn_mfma_f32_16x16x32_f16( \
        *(const half8*)(AR + (size_t)(off) + (size_t)lane * 8), bf, acc, 0, 0, 0)

__global__ __launch_bounds__(256, 4) void flow_kernel(
    const float* __restrict__ traj,
    const float* __restrict__ start,
    const float* __restrict__ goal,
    const float* __restrict__ lu_bias,
    const float* __restrict__ cn_b0,
    const float* __restrict__ cn_ctxb,
    const float* __restrict__ cn_l1b,
    const float* __restrict__ cn_l2b,
    const float* __restrict__ cn_bf,
    const float* __restrict__ enc_b1,
    const float* __restrict__ enc_b2,
    const _Float16* __restrict__ AR,
    const float* __restrict__ wsLd,
    float* __restrict__ out, int B)
{
    __shared__ __align__(16) _Float16 ActX[64 * 104];  // x features(72)+zeros, stride 104
    __shared__ __align__(16) _Float16 ActH[64 * 72];   // h_id(36)+ctx(8)+zeros, stride 72
    __shared__ __align__(16) _Float16 ActT[64 * 72];   // hidden scratch, stride 72

    const int tid  = threadIdx.x;
    const int lane = tid & 63;
    const int w    = __builtin_amdgcn_readfirstlane(tid >> 6);
    const int n    = lane & 15, lg = lane >> 4;
    const int bg0  = blockIdx.x * 64;

    // ---- init: stage x and ctx into LDS ----
    #pragma unroll
    for (int r = 0; r < 9; ++r) {                       // 64*36 float2 = 2304
        int e = tid + 256 * r;
        int b = e / 36, p = e % 36;
        float2 v = *(const float2*)(traj + (size_t)(bg0 + b) * DD + 2 * p);
        ActX[b * 104 + 2 * p]     = (_Float16)v.x;
        ActX[b * 104 + 2 * p + 1] = (_Float16)v.y;
    }
    #pragma unroll
    for (int r = 0; r < 8; ++r) {                       // zero cols 72..103
        int e = tid + 256 * r;
        int b = e / 32, c = 72 + e % 32;
        ActX[b * 104 + c] = (_Float16)0.f;
    }
    {                                                   // ctx -> ActH cols 36..43
        int b = tid >> 2, cp = tid & 3;
        const float* s = (cp < 2) ? (start + (size_t)(bg0 + b) * 4 + 2 * cp)
                                  : (goal  + (size_t)(bg0 + b) * 4 + 2 * (cp - 2));
        ActH[b * 72 + 36 + 2 * cp]     = (_Float16)s[0];
        ActH[b * 72 + 36 + 2 * cp + 1] = (_Float16)s[1];
    }
    #pragma unroll
    for (int r = 0; r < 7; ++r) {                       // zero ActH cols 44..71
        int e = tid + 256 * r;
        int b = e / 28, c = 44 + e % 28;
        ActH[b * 72 + c] = (_Float16)0.f;
    }
    __syncthreads();   // the ONLY barrier: init crosses wave ownership

    const int bx = (16 * w + n) * 104;
    const int bh = (16 * w + n) * 72;
    const int bt = (16 * w + n) * 72;

    float ld_acc = 0.f;
    const f32x4 z4 = {0.f, 0.f, 0.f, 0.f};

    #pragma unroll 1
    for (int blk = 0; blk < NBLK; ++blk) {
        const size_t B0 = (size_t)blk * PB;

        // ---- step1: y = W @ x + lu_bias ----
        half8 bx0 = *(const half8*)&ActX[bx + 0  + lg * 8];
        half8 bx1 = *(const half8*)&ActX[bx + 32 + lg * 8];
        half8 bx2 = *(const half8*)&ActX[bx + 64 + lg * 8];
        f32x4 y[5];
        #pragma unroll
        for (int mt = 0; mt < 5; ++mt) {
            f32x4 a = z4;
            MFMA_A(a, B0 + S1O + (mt * 3 + 0) * 512, bx0);
            MFMA_A(a, B0 + S1O + (mt * 3 + 1) * 512, bx1);
            MFMA_A(a, B0 + S1O + (mt * 3 + 2) * 512, bx2);
            int bm = mt * 16 + lg * 4; if (bm > 68) bm = 68;
            const float4 bb = *(const float4*)(lu_bias + blk * DD + bm);
            y[mt][0] = a[0] + bb.x; y[mt][1] = a[1] + bb.y;
            y[mt][2] = a[2] + bb.z; y[mt][3] = a[3] + bb.w;
        }
        // h_id (rows 36..71) -> ActX (in place) and ActH (cols 0..35)
        if (lg >= 1) { half4 hv = pk4(y[2]); int m0 = 32 + lg * 4;
            *(half4*)&ActX[bx + m0] = hv; *(half4*)&ActH[bh + m0 - 36] = hv; }
        {            half4 hv = pk4(y[3]); int m0 = 48 + lg * 4;
            *(half4*)&ActX[bx + m0] = hv; *(half4*)&ActH[bh + m0 - 36] = hv; }
        if (lg < 2) { half4 hv = pk4(y[4]); int m0 = 64 + lg * 4;
            *(half4*)&ActX[bx + m0] = hv; *(half4*)&ActH[bh + m0 - 36] = hv; }

        // ---- step2: t = W0 @ [h_id; ctx] + b0 ----
        half8 bh0 = *(const half8*)&ActH[bh + 0  + lg * 8];
        half8 bh1 = *(const half8*)&ActH[bh + 32 + lg * 8];
        f32x4 t[4];
        #pragma unroll
        for (int mt = 0; mt < 4; ++mt) {
            f32x4 a = z4;
            MFMA_A(a, B0 + S2O + (mt * 2 + 0) * 512, bh0);
            MFMA_A(a, B0 + S2O + (mt * 2 + 1) * 512, bh1);
            const float4 bb = *(const float4*)(cn_b0 + blk * 64 + mt * 16 + lg * 4);
            t[mt][0] = a[0] + bb.x; t[mt][1] = a[1] + bb.y;
            t[mt][2] = a[2] + bb.z; t[mt][3] = a[3] + bb.w;
        }

        // ---- two residual blocks ----
        #pragma unroll 1
        for (int i = 0; i < 2; ++i) {
            const size_t RB = B0 + RBO + (size_t)i * 10240;
            #pragma unroll
            for (int mt = 0; mt < 4; ++mt)
                *(half4*)&ActT[bt + mt * 16 + lg * 4] = pk4r(t[mt]);   // relu(t)
            half8 bt0 = *(const half8*)&ActT[bt + 0  + lg * 8];
            half8 bt1 = *(const half8*)&ActT[bt + 32 + lg * 8];
            f32x4 a1[4];
            #pragma unroll
            for (int mt = 0; mt < 4; ++mt) {
                f32x4 a = z4;
                MFMA_A(a, RB + RB_L1 + (mt * 2 + 0) * 512, bt0);
                MFMA_A(a, RB + RB_L1 + (mt * 2 + 1) * 512, bt1);
                const float4 bb = *(const float4*)(cn_l1b + (blk * 2 + i) * 64 + mt * 16 + lg * 4);
                a1[mt][0] = a[0] + bb.x; a1[mt][1] = a[1] + bb.y;
                a1[mt][2] = a[2] + bb.z; a1[mt][3] = a[3] + bb.w;
            }
            #pragma unroll
            for (int mt = 0; mt < 4; ++mt)
                *(half4*)&ActT[bt + mt * 16 + lg * 4] = pk4r(a1[mt]);  // relu(a1)
            bt0 = *(const half8*)&ActT[bt + 0  + lg * 8];
            bt1 = *(const half8*)&ActT[bt + 32 + lg * 8];
            #pragma unroll
            for (int mt = 0; mt < 4; ++mt) {
                f32x4 a = z4;
                MFMA_A(a, RB + RB_L2 + (mt * 2 + 0) * 512, bt0);
                MFMA_A(a, RB + RB_L2 + (mt * 2 + 1) * 512, bt1);
                const float4 b2 = *(const float4*)(cn_l2b + (blk * 2 + i) * 64 + mt * 16 + lg * 4);
                f32x4 g = z4;
                MFMA_A(g, RB + RB_GW + mt * 512, bh1);
                const float4 cb = *(const float4*)(cn_ctxb + (blk * 2 + i) * 64 + mt * 16 + lg * 4);
                #pragma unroll
                for (int r = 0; r < 4; ++r) {
                    float a2 = a[r] + ((const float*)&b2)[r];
                    float gg = 1.f / (1.f + expf(-(g[r] + ((const float*)&cb)[r])));
                    t[mt][r] = fmaf(a2, gg, t[mt][r]);
                }
            }
        }

        // ---- step4: params = Wf @ t + bf ----
        #pragma unroll
        for (int mt = 0; mt < 4; ++mt)
            *(half4*)&ActT[bt + mt * 16 + lg * 4] = pk4(t[mt]);        // raw t
        half8 bt0 = *(const half8*)&ActT[bt + 0  + lg * 8];
        half8 bt1 = *(const half8*)&ActT[bt + 32 + lg * 8];
        f32x4 p[5];
        #pragma unroll
        for (int mt = 0; mt < 5; ++mt) {
            f32x4 a = z4;
            MFMA_A(a, B0 + S4O + (mt * 2 + 0) * 512, bt0);
            MFMA_A(a, B0 + S4O + (mt * 2 + 1) * 512, bt1);
            int bm = mt * 16 + lg * 4; if (bm > 68) bm = 68;
            const float4 bb = *(const float4*)(cn_bf + blk * DD + bm);
            p[mt][0] = a[0] + bb.x; p[mt][1] = a[1] + bb.y;
            p[mt][2] = a[2] + bb.z; p[mt][3] = a[3] + bb.w;
        }
        // scale rows (param 36..71): sigmoid, logdet, stash to ActT cols 0..35
        if (lg >= 1) {
            f32x4 s;
            #pragma unroll
            for (int r = 0; r < 4; ++r) {
                s[r] = 1.f / (1.f + expf(-(p[2][r] + 2.f))) + 0.001f;
                ld_acc += logf(s[r]);
            }
            *(half4*)&ActT[bt + (32 + lg * 4) - 36] = pk4(s);
        }
        {
            f32x4 s;
            #pragma unroll
            for (int r = 0; r < 4; ++r) {
                s[r] = 1.f / (1.f + expf(-(p[3][r] + 2.f))) + 0.001f;
                ld_acc += logf(s[r]);
            }
            *(half4*)&ActT[bt + (48 + lg * 4) - 36] = pk4(s);
        }
        if (lg < 2) {
            f32x4 s;
            #pragma unroll
            for (int r = 0; r < 4; ++r) {
                s[r] = 1.f / (1.f + expf(-(p[4][r] + 2.f))) + 0.001f;
                ld_acc += logf(s[r]);
            }
            *(half4*)&ActT[bt + (64 + lg * 4) - 36] = pk4(s);
        }
        // combine: x_new[m<36] = y*scale + shift -> ActX
        {
            half4 sv = *(const half4*)&ActT[bt + lg * 4];
            f32x4 xn;
            #pragma unroll
            for (int r = 0; r < 4; ++r) xn[r] = fmaf(y[0][r], (float)sv[r], p[0][r]);
            *(half4*)&ActX[bx + lg * 4] = pk4(xn);
        }
        {
            half4 sv = *(const half4*)&ActT[bt + 16 + lg * 4];
            f32x4 xn;
            #pragma unroll
            for (int r = 0; r < 4; ++r) xn[r] = fmaf(y[1][r], (float)sv[r], p[1][r]);
            *(half4*)&ActX[bx + 16 + lg * 4] = pk4(xn);
        }
        if (lg == 0) {
            half4 sv = *(const half4*)&ActT[bt + 32];
            f32x4 xn;
            #pragma unroll
            for (int r = 0; r < 4; ++r) xn[r] = fmaf(y[2][r], (float)sv[r], p[2][r]);
            *(half4*)&ActX[bx + 32] = pk4(xn);
        }
    }

    // ---- encoder head ----
    half8 bh1 = *(const half8*)&ActH[bh + 32 + lg * 8];
    #pragma unroll
    for (int mt = 0; mt < 4; ++mt) {
        f32x4 a = z4;
        MFMA_A(a, E1O + mt * 512, bh1);
        const float4 bb = *(const float4*)(enc_b1 + mt * 16 + lg * 4);
        f32x4 h;
        h[0] = a[0] + bb.x; h[1] = a[1] + bb.y; h[2] = a[2] + bb.z; h[3] = a[3] + bb.w;
        *(half4*)&ActT[bt + mt * 16 + lg * 4] = pk4r(h);               // relu(h)
    }
    half8 bt0 = *(const half8*)&ActT[bt + 0  + lg * 8];
    half8 bt1 = *(const half8*)&ActT[bt + 32 + lg * 8];
    f32x4 me[9];
    #pragma unroll
    for (int mt = 0; mt < 9; ++mt) {
        f32x4 a = z4;
        MFMA_A(a, E2O + (mt * 2 + 0) * 512, bt0);
        MFMA_A(a, E2O + (mt * 2 + 1) * 512, bt1);
        const float4 bb = *(const float4*)(enc_b2 + mt * 16 + lg * 4);
        me[mt][0] = a[0] + bb.x; me[mt][1] = a[1] + bb.y;
        me[mt][2] = a[2] + bb.z; me[mt][3] = a[3] + bb.w;
    }
    // lsd rows (param 72..143) -> ActT cols 0..71 (f16); sls on those lanes
    float slsp = 0.f, qp = 0.f;
    if (lg >= 2) {
        #pragma unroll
        for (int r = 0; r < 4; ++r) slsp += me[4][r];
        *(half4*)&ActT[bt + lg * 4 - 8] = pk4(me[4]);
    }
    #pragma unroll
    for (int mt = 5; mt < 9; ++mt) {
        #pragma unroll
        for (int r = 0; r < 4; ++r) slsp += me[mt][r];
        *(half4*)&ActT[bt + (mt * 16 + lg * 4) - 72] = pk4(me[mt]);
    }
    // q on mean lanes: z = (x - mean) * exp(-lsd)
    #pragma unroll
    for (int mt = 0; mt < 4; ++mt) {
        int m0 = mt * 16 + lg * 4;
        half4 xv = *(const half4*)&ActX[bx + m0];
        half4 lv = *(const half4*)&ActT[bt + m0];
        #pragma unroll
        for (int r = 0; r < 4; ++r) {
            float zz = ((float)xv[r] - me[mt][r]) * expf(-(float)lv[r]);
            qp = fmaf(zz, zz, qp);
        }
    }
    if (lg < 2) {
        int m0 = 64 + lg * 4;
        half4 xv = *(const half4*)&ActX[bx + m0];
        half4 lv = *(const half4*)&ActT[bt + m0];
        #pragma unroll
        for (int r = 0; r < 4; ++r) {
            float zz = ((float)xv[r] - me[4][r]) * expf(-(float)lv[r]);
            qp = fmaf(zz, zz, qp);
        }
    }

    // ---- reduce across the 4 lane-groups sharing n, and write ----
    qp     += __shfl_xor(qp, 16);     qp     += __shfl_xor(qp, 32);
    slsp   += __shfl_xor(slsp, 16);   slsp   += __shfl_xor(slsp, 32);
    ld_acc += __shfl_xor(ld_acc, 16); ld_acc += __shfl_xor(ld_acc, 32);
    if (lane < 16) {
        float ldsum = 0.f;
        #pragma unroll
        for (int k = 0; k < NBLK; ++k) ldsum += wsLd[k];
        // 0.5 * 72 * log(2*pi) = 66.16357439
        out[bg0 + 16 * w + lane] = -0.5f * qp - slsp - 66.1635744f + ld_acc + ldsum;
    }
}

// ---------------------------------------------------------------------------
extern "C" void kernel_launch(void* const* d_in, const int* in_sizes, int n_in,
                              void* d_out, int out_size, void* d_ws, size_t ws_size,
                              hipStream_t stream) {
    const float* traj     = (const float*)d_in[0];
    const float* start    = (const float*)d_in[1];
    const float* goal     = (const float*)d_in[2];
    const float* lu_lower = (const float*)d_in[3];
    const float* lu_upper = (const float*)d_in[4];
    const float* lu_diag  = (const float*)d_in[5];
    const float* lu_bias  = (const float*)d_in[6];
    const float* cn_W0    = (const float*)d_in[7];
    const float* cn_b0    = (const float*)d_in[8];
    const float* cn_ctxW  = (const float*)d_in[9];
    const float* cn_ctxb  = (const float*)d_in[10];
    const float* cn_l1W   = (const float*)d_in[11];
    const float* cn_l1b   = (const float*)d_in[12];
    const float* cn_l2W   = (const float*)d_in[13];
    const float* cn_l2b   = (const float*)d_in[14];
    const float* cn_Wf    = (const float*)d_in[15];
    const float* cn_bf    = (const float*)d_in[16];
    const float* enc_W1   = (const float*)d_in[17];
    const float* enc_b1   = (const float*)d_in[18];
    const float* enc_W2   = (const float*)d_in[19];
    const float* enc_b2   = (const float*)d_in[20];

    float* outp = (float*)d_out;
    const int B = in_sizes[0] / DD;

    float*     wsLd = (float*)d_ws;                           // 16 f32
    _Float16*  AR   = (_Float16*)((char*)d_ws + 256);         // 609280 f16

    hipLaunchKernelGGL(prep_lu, dim3(NBLK), dim3(256), 0, stream,
                       lu_lower, lu_upper, lu_diag, AR, wsLd);
    hipLaunchKernelGGL(prep_w, dim3((950 * 64 + 255) / 256), dim3(256), 0, stream,
                       cn_W0, cn_ctxW, cn_l1W, cn_l2W, cn_Wf, enc_W1, enc_W2, AR);

    hipLaunchKernelGGL(flow_kernel, dim3(B / 64), dim3(256), 0, stream,
                       traj, start, goal, lu_bias,
                       cn_b0, cn_ctxb, cn_l1b, cn_l2b, cn_bf,
                       enc_b1, enc_b2, AR, wsLd, outp, B);
}

// Round 7
// 453.361 us; speedup vs baseline: 15.8773x; 1.3208x over previous
//
#include <hip/hip_runtime.h>
#include <math.h>

#define DD   72
#define MID  36
#define NBLK 16

typedef _Float16 half8 __attribute__((ext_vector_type(8)));
typedef _Float16 half4 __attribute__((ext_vector_type(4)));
typedef float    f32x4 __attribute__((ext_vector_type(4)));

// ---- A-fragment arena layout (f16 units). Each frag = 64 lanes x 8 f16 = 512.
#define PB    37376            // per-block total
#define S1O   0                // step1 LU matmul: 5 mtiles x 3 ktiles = 15 frags
#define S2O   7680             // step2 W0: 4 x 2 = 8 frags
#define RBO   11776            // resblocks: per i (0/1) stride 10240
#define RB_L1 0                //   l1: 8 frags
#define RB_L2 4096             //   l2: 8 frags
#define RB_GW 8192             //   gate: 4 frags (ktile1 only)
#define S4O   32256            // step4 Wf: 5 x 2 = 10 frags
#define E1O   (16 * PB)        // enc W1: 4 frags
#define E2O   (E1O + 2048)     // enc W2: 9 x 2 = 18 frags
#define AR_TOTAL (E2O + 18 * 512)   // 609280 f16 = 1218560 B

__device__ inline half4 pk4(f32x4 v) {
    half4 h; h[0] = (_Float16)v[0]; h[1] = (_Float16)v[1];
    h[2] = (_Float16)v[2]; h[3] = (_Float16)v[3]; return h;
}
__device__ inline half4 pk4r(f32x4 v) {   // relu + pack
    half4 h;
    h[0] = (_Float16)fmaxf(v[0], 0.f); h[1] = (_Float16)fmaxf(v[1], 0.f);
    h[2] = (_Float16)fmaxf(v[2], 0.f); h[3] = (_Float16)fmaxf(v[3], 0.f);
    return h;
}
// fast sigmoid: v_exp + v_add + v_rcp (vs ~20-inst libm expf)
__device__ inline float sigf(float x) {
    return __fdividef(1.f, 1.f + __expf(-x));
}

// ---------------------------------------------------------------------------
// Prep 1: LU-composed W -> step1 A-frags. LDS-staged (round-6 version was
// latency-bound on uncoalesced global reads with 1 wave/SIMD: ~200 us).
// ---------------------------------------------------------------------------
__global__ __launch_bounds__(256) void prep_lu(
    const float* __restrict__ lu_lower,
    const float* __restrict__ lu_upper,
    const float* __restrict__ lu_diag,
    _Float16* __restrict__ AR, float* __restrict__ wsLd)
{
    const int blk = blockIdx.x, tid = threadIdx.x;
    __shared__ float Ls[DD][DD + 1];   // +1 pad: stride 73 = 9 mod 32, conflict-free
    __shared__ float Us[DD][DD + 1];
    __shared__ float diag[DD], ldp[DD];

    const float* L = lu_lower + blk * DD * DD;
    const float* U = lu_upper + blk * DD * DD;
    for (int e = tid; e < DD * DD; e += 256) {
        Ls[e / DD][e % DD] = L[e];
        Us[e / DD][e % DD] = U[e];
    }
    if (tid < DD) {
        float v  = lu_diag[blk * DD + tid];
        float sp = log1pf(expf(v)) + 0.001f;
        diag[tid] = sp; ldp[tid] = logf(sp);
    }
    __syncthreads();
    if (tid == 0) { float s = 0.f; for (int i = 0; i < DD; ++i) s += ldp[i]; wsLd[blk] = s; }

    for (int s = tid; s < 15 * 64; s += 256) {
        int frag = s >> 6, lane = s & 63;
        int mt = frag / 3, kt = frag % 3;
        int m  = mt * 16 + (lane & 15);
        int k0 = kt * 32 + (lane >> 4) * 8;
        half8 hv;
        #pragma unroll
        for (int j = 0; j < 8; ++j) {
            int k = k0 + j;
            float v = 0.f;
            if (m < DD && k < DD) {
                int mm = m < k ? m : k;
                for (int kk = 0; kk <= mm; ++kk) {
                    float a = (kk < m) ? Ls[m][kk] : 1.0f;
                    float b = (kk < k) ? Us[kk][k] : diag[k];
                    v = fmaf(a, b, v);
                }
            }
            hv[j] = (_Float16)v;
        }
        *(half8*)(AR + (size_t)blk * PB + S1O + (size_t)frag * 512 + (size_t)lane * 8) = hv;
    }
}

// ---------------------------------------------------------------------------
// Prep 2: all static weights -> A-frags (950 frags x 64 lanes)
// ---------------------------------------------------------------------------
__global__ __launch_bounds__(256) void prep_w(
    const float* __restrict__ cn_W0, const float* __restrict__ cn_ctxW,
    const float* __restrict__ cn_l1W, const float* __restrict__ cn_l2W,
    const float* __restrict__ cn_Wf, const float* __restrict__ enc_W1,
    const float* __restrict__ enc_W2, _Float16* __restrict__ AR)
{
    int gid = blockIdx.x * 256 + threadIdx.x;
    int fid = gid >> 6, lane = gid & 63;
    if (fid >= 950) return;
    const int mrow = lane & 15, kcol0 = (lane >> 4) * 8;

    const float* src = nullptr; size_t dst = 0;
    int m = 0, kbase = 0, rows = 64, kv_lo = 0, kv_hi = 64, sstr = 64, ksub = 0;

    if (fid < 128) {                    // step2 W0 [64 x 44] over ActH k
        int blk = fid >> 3, f = fid & 7;
        int mt = f >> 1, kt = f & 1;
        src = cn_W0 + (size_t)blk * 64 * 44; sstr = 44;
        dst = (size_t)blk * PB + S2O + (size_t)f * 512;
        m = mt * 16 + mrow; kbase = kt * 32 + kcol0; kv_hi = 44;
    } else if (fid < 384) {             // l1 [64 x 64]
        int id = fid - 128, bi = id >> 3, f = id & 7;
        int mt = f >> 1, kt = f & 1;
        src = cn_l1W + (size_t)bi * 4096;
        dst = (size_t)(bi >> 1) * PB + RBO + (size_t)(bi & 1) * 10240 + RB_L1 + (size_t)f * 512;
        m = mt * 16 + mrow; kbase = kt * 32 + kcol0;
    } else if (fid < 640) {             // l2 [64 x 64]
        int id = fid - 384, bi = id >> 3, f = id & 7;
        int mt = f >> 1, kt = f & 1;
        src = cn_l2W + (size_t)bi * 4096;
        dst = (size_t)(bi >> 1) * PB + RBO + (size_t)(bi & 1) * 10240 + RB_L2 + (size_t)f * 512;
        m = mt * 16 + mrow; kbase = kt * 32 + kcol0;
    } else if (fid < 768) {             // gate cW [64 x 8] at ActH k 36..43, ktile1
        int id = fid - 640, bi = id >> 2, mt = id & 3;
        src = cn_ctxW + (size_t)bi * 512; sstr = 8;
        dst = (size_t)(bi >> 1) * PB + RBO + (size_t)(bi & 1) * 10240 + RB_GW + (size_t)mt * 512;
        m = mt * 16 + mrow; kbase = 32 + kcol0; kv_lo = 36; kv_hi = 44; ksub = 36;
    } else if (fid < 928) {             // step4 Wf [72 x 64]
        int id = fid - 768, blk = id / 10, f = id % 10;
        int mt = f >> 1, kt = f & 1;
        src = cn_Wf + (size_t)blk * 4608;
        dst = (size_t)blk * PB + S4O + (size_t)f * 512;
        m = mt * 16 + mrow; kbase = kt * 32 + kcol0; rows = 72;
    } else if (fid < 932) {             // enc W1 [64 x 8] at ActH k 36..43
        int mt = fid - 928;
        src = enc_W1; sstr = 8;
        dst = E1O + (size_t)mt * 512;
        m = mt * 16 + mrow; kbase = 32 + kcol0; kv_lo = 36; kv_hi = 44; ksub = 36;
    } else {                            // enc W2 [144 x 64]
        int id = fid - 932, mt = id >> 1, kt = id & 1;
        src = enc_W2;
        dst = E2O + (size_t)id * 512;
        m = mt * 16 + mrow; kbase = kt * 32 + kcol0; rows = 144;
    }
    half8 hv;
    #pragma unroll
    for (int j = 0; j < 8; ++j) {
        int k = kbase + j;
        float v = 0.f;
        if (m < rows && k >= kv_lo && k < kv_hi)
            v = src[(size_t)m * sstr + (k - ksub)];
        hv[j] = (_Float16)v;
    }
    *(half8*)(AR + dst + (size_t)lane * 8) = hv;
}

// ---------------------------------------------------------------------------
// Flow kernel: 4 waves/wg, each wave owns 16 batch rows. MFMA 16x16x32 f16.
// Act* LDS buffers are batch-row-partitioned per wave -> no inner barriers.
// ---------------------------------------------------------------------------
#define MFMA_A(acc, off, bf) \
    acc = __builtin_amdgcn_mfma_f32_16x16x32_f16( \
        *(const half8*)(AR + (size_t)(off) + (size_t)lane * 8), bf, acc, 0, 0, 0)

__global__ __launch_bounds__(256, 4) void flow_kernel(
    const float* __restrict__ traj,
    const float* __restrict__ start,
    const float* __restrict__ goal,
    const float* __restrict__ lu_bias,
    const float* __restrict__ cn_b0,
    const float* __restrict__ cn_ctxb,
    const float* __restrict__ cn_l1b,
    const float* __restrict__ cn_l2b,
    const float* __restrict__ cn_bf,
    const float* __restrict__ enc_b1,
    const float* __restrict__ enc_b2,
    const _Float16* __restrict__ AR,
    const float* __restrict__ wsLd,
    float* __restrict__ out, int B)
{
    __shared__ __align__(16) _Float16 ActX[64 * 104];  // x features(72)+zeros, stride 104
    __shared__ __align__(16) _Float16 ActH[64 * 72];   // h_id(36)+ctx(8)+zeros, stride 72
    __shared__ __align__(16) _Float16 ActT[64 * 72];   // hidden scratch, stride 72

    const int tid  = threadIdx.x;
    const int lane = tid & 63;
    const int w    = __builtin_amdgcn_readfirstlane(tid >> 6);
    const int n    = lane & 15, lg = lane >> 4;
    const int bg0  = blockIdx.x * 64;

    // ---- init: stage x and ctx into LDS ----
    #pragma unroll
    for (int r = 0; r < 9; ++r) {                       // 64*36 float2 = 2304
        int e = tid + 256 * r;
        int b = e / 36, p = e % 36;
        float2 v = *(const float2*)(traj + (size_t)(bg0 + b) * DD + 2 * p);
        ActX[b * 104 + 2 * p]     = (_Float16)v.x;
        ActX[b * 104 + 2 * p + 1] = (_Float16)v.y;
    }
    #pragma unroll
    for (int r = 0; r < 8; ++r) {                       // zero cols 72..103
        int e = tid + 256 * r;
        int b = e / 32, c = 72 + e % 32;
        ActX[b * 104 + c] = (_Float16)0.f;
    }
    {                                                   // ctx -> ActH cols 36..43
        int b = tid >> 2, cp = tid & 3;
        const float* s = (cp < 2) ? (start + (size_t)(bg0 + b) * 4 + 2 * cp)
                                  : (goal  + (size_t)(bg0 + b) * 4 + 2 * (cp - 2));
        ActH[b * 72 + 36 + 2 * cp]     = (_Float16)s[0];
        ActH[b * 72 + 36 + 2 * cp + 1] = (_Float16)s[1];
    }
    #pragma unroll
    for (int r = 0; r < 7; ++r) {                       // zero ActH cols 44..71
        int e = tid + 256 * r;
        int b = e / 28, c = 44 + e % 28;
        ActH[b * 72 + c] = (_Float16)0.f;
    }
    __syncthreads();   // the ONLY barrier: init crosses wave ownership

    const int bx = (16 * w + n) * 104;
    const int bh = (16 * w + n) * 72;
    const int bt = (16 * w + n) * 72;

    float ld_acc = 0.f;
    const f32x4 z4 = {0.f, 0.f, 0.f, 0.f};

    #pragma unroll 1
    for (int blk = 0; blk < NBLK; ++blk) {
        const size_t B0 = (size_t)blk * PB;

        // ---- step1: y = W @ x + lu_bias ----
        half8 bx0 = *(const half8*)&ActX[bx + 0  + lg * 8];
        half8 bx1 = *(const half8*)&ActX[bx + 32 + lg * 8];
        half8 bx2 = *(const half8*)&ActX[bx + 64 + lg * 8];
        f32x4 y[5];
        #pragma unroll
        for (int mt = 0; mt < 5; ++mt) {
            f32x4 a = z4;
            MFMA_A(a, B0 + S1O + (mt * 3 + 0) * 512, bx0);
            MFMA_A(a, B0 + S1O + (mt * 3 + 1) * 512, bx1);
            MFMA_A(a, B0 + S1O + (mt * 3 + 2) * 512, bx2);
            int bm = mt * 16 + lg * 4; if (bm > 68) bm = 68;
            const float4 bb = *(const float4*)(lu_bias + blk * DD + bm);
            y[mt][0] = a[0] + bb.x; y[mt][1] = a[1] + bb.y;
            y[mt][2] = a[2] + bb.z; y[mt][3] = a[3] + bb.w;
        }
        // h_id (rows 36..71) -> ActX (in place) and ActH (cols 0..35)
        if (lg >= 1) { half4 hv = pk4(y[2]); int m0 = 32 + lg * 4;
            *(half4*)&ActX[bx + m0] = hv; *(half4*)&ActH[bh + m0 - 36] = hv; }
        {            half4 hv = pk4(y[3]); int m0 = 48 + lg * 4;
            *(half4*)&ActX[bx + m0] = hv; *(half4*)&ActH[bh + m0 - 36] = hv; }
        if (lg < 2) { half4 hv = pk4(y[4]); int m0 = 64 + lg * 4;
            *(half4*)&ActX[bx + m0] = hv; *(half4*)&ActH[bh + m0 - 36] = hv; }

        // ---- step2: t = W0 @ [h_id; ctx] + b0 ----
        half8 bh0 = *(const half8*)&ActH[bh + 0  + lg * 8];
        half8 bh1 = *(const half8*)&ActH[bh + 32 + lg * 8];
        f32x4 t[4];
        #pragma unroll
        for (int mt = 0; mt < 4; ++mt) {
            f32x4 a = z4;
            MFMA_A(a, B0 + S2O + (mt * 2 + 0) * 512, bh0);
            MFMA_A(a, B0 + S2O + (mt * 2 + 1) * 512, bh1);
            const float4 bb = *(const float4*)(cn_b0 + blk * 64 + mt * 16 + lg * 4);
            t[mt][0] = a[0] + bb.x; t[mt][1] = a[1] + bb.y;
            t[mt][2] = a[2] + bb.z; t[mt][3] = a[3] + bb.w;
        }

        // ---- two residual blocks ----
        #pragma unroll 1
        for (int i = 0; i < 2; ++i) {
            const size_t RB = B0 + RBO + (size_t)i * 10240;
            #pragma unroll
            for (int mt = 0; mt < 4; ++mt)
                *(half4*)&ActT[bt + mt * 16 + lg * 4] = pk4r(t[mt]);   // relu(t)
            half8 bt0 = *(const half8*)&ActT[bt + 0  + lg * 8];
            half8 bt1 = *(const half8*)&ActT[bt + 32 + lg * 8];
            f32x4 a1[4];
            #pragma unroll
            for (int mt = 0; mt < 4; ++mt) {
                f32x4 a = z4;
                MFMA_A(a, RB + RB_L1 + (mt * 2 + 0) * 512, bt0);
                MFMA_A(a, RB + RB_L1 + (mt * 2 + 1) * 512, bt1);
                const float4 bb = *(const float4*)(cn_l1b + (blk * 2 + i) * 64 + mt * 16 + lg * 4);
                a1[mt][0] = a[0] + bb.x; a1[mt][1] = a[1] + bb.y;
                a1[mt][2] = a[2] + bb.z; a1[mt][3] = a[3] + bb.w;
            }
            #pragma unroll
            for (int mt = 0; mt < 4; ++mt)
                *(half4*)&ActT[bt + mt * 16 + lg * 4] = pk4r(a1[mt]);  // relu(a1)
            bt0 = *(const half8*)&ActT[bt + 0  + lg * 8];
            bt1 = *(const half8*)&ActT[bt + 32 + lg * 8];
            #pragma unroll
            for (int mt = 0; mt < 4; ++mt) {
                f32x4 a = z4;
                MFMA_A(a, RB + RB_L2 + (mt * 2 + 0) * 512, bt0);
                MFMA_A(a, RB + RB_L2 + (mt * 2 + 1) * 512, bt1);
                const float4 b2 = *(const float4*)(cn_l2b + (blk * 2 + i) * 64 + mt * 16 + lg * 4);
                f32x4 g = z4;
                MFMA_A(g, RB + RB_GW + mt * 512, bh1);
                const float4 cb = *(const float4*)(cn_ctxb + (blk * 2 + i) * 64 + mt * 16 + lg * 4);
                #pragma unroll
                for (int r = 0; r < 4; ++r) {
                    float a2 = a[r] + ((const float*)&b2)[r];
                    float gg = sigf(g[r] + ((const float*)&cb)[r]);
                    t[mt][r] = fmaf(a2, gg, t[mt][r]);
                }
            }
        }

        // ---- step4: params = Wf @ t + bf ----
        #pragma unroll
        for (int mt = 0; mt < 4; ++mt)
            *(half4*)&ActT[bt + mt * 16 + lg * 4] = pk4(t[mt]);        // raw t
        half8 bt0 = *(const half8*)&ActT[bt + 0  + lg * 8];
        half8 bt1 = *(const half8*)&ActT[bt + 32 + lg * 8];
        f32x4 p[5];
        #pragma unroll
        for (int mt = 0; mt < 5; ++mt) {
            f32x4 a = z4;
            MFMA_A(a, B0 + S4O + (mt * 2 + 0) * 512, bt0);
            MFMA_A(a, B0 + S4O + (mt * 2 + 1) * 512, bt1);
            int bm = mt * 16 + lg * 4; if (bm > 68) bm = 68;
            const float4 bb = *(const float4*)(cn_bf + blk * DD + bm);
            p[mt][0] = a[0] + bb.x; p[mt][1] = a[1] + bb.y;
            p[mt][2] = a[2] + bb.z; p[mt][3] = a[3] + bb.w;
        }
        // scale rows (param 36..71): sigmoid, logdet, stash to ActT cols 0..35
        if (lg >= 1) {
            f32x4 s;
            #pragma unroll
            for (int r = 0; r < 4; ++r) {
                s[r] = sigf(p[2][r] + 2.f) + 0.001f;
                ld_acc += __logf(s[r]);
            }
            *(half4*)&ActT[bt + (32 + lg * 4) - 36] = pk4(s);
        }
        {
            f32x4 s;
            #pragma unroll
            for (int r = 0; r < 4; ++r) {
                s[r] = sigf(p[3][r] + 2.f) + 0.001f;
                ld_acc += __logf(s[r]);
            }
            *(half4*)&ActT[bt + (48 + lg * 4) - 36] = pk4(s);
        }
        if (lg < 2) {
            f32x4 s;
            #pragma unroll
            for (int r = 0; r < 4; ++r) {
                s[r] = sigf(p[4][r] + 2.f) + 0.001f;
                ld_acc += __logf(s[r]);
            }
            *(half4*)&ActT[bt + (64 + lg * 4) - 36] = pk4(s);
        }
        // combine: x_new[m<36] = y*scale + shift -> ActX
        {
            half4 sv = *(const half4*)&ActT[bt + lg * 4];
            f32x4 xn;
            #pragma unroll
            for (int r = 0; r < 4; ++r) xn[r] = fmaf(y[0][r], (float)sv[r], p[0][r]);
            *(half4*)&ActX[bx + lg * 4] = pk4(xn);
        }
        {
            half4 sv = *(const half4*)&ActT[bt + 16 + lg * 4];
            f32x4 xn;
            #pragma unroll
            for (int r = 0; r < 4; ++r) xn[r] = fmaf(y[1][r], (float)sv[r], p[1][r]);
            *(half4*)&ActX[bx + 16 + lg * 4] = pk4(xn);
        }
        if (lg == 0) {
            half4 sv = *(const half4*)&ActT[bt + 32];
            f32x4 xn;
            #pragma unroll
            for (int r = 0; r < 4; ++r) xn[r] = fmaf(y[2][r], (float)sv[r], p[2][r]);
            *(half4*)&ActX[bx + 32] = pk4(xn);
        }
    }

    // ---- encoder head ----
    half8 bh1 = *(const half8*)&ActH[bh + 32 + lg * 8];
    #pragma unroll
    for (int mt = 0; mt < 4; ++mt) {
        f32x4 a = z4;
        MFMA_A(a, E1O + mt * 512, bh1);
        const float4 bb = *(const float4*)(enc_b1 + mt * 16 + lg * 4);
        f32x4 h;
        h[0] = a[0] + bb.x; h[1] = a[1] + bb.y; h[2] = a[2] + bb.z; h[3] = a[3] + bb.w;
        *(half4*)&ActT[bt + mt * 16 + lg * 4] = pk4r(h);               // relu(h)
    }
    half8 bt0 = *(const half8*)&ActT[bt + 0  + lg * 8];
    half8 bt1 = *(const half8*)&ActT[bt + 32 + lg * 8];
    f32x4 me[9];
    #pragma unroll
    for (int mt = 0; mt < 9; ++mt) {
        f32x4 a = z4;
        MFMA_A(a, E2O + (mt * 2 + 0) * 512, bt0);
        MFMA_A(a, E2O + (mt * 2 + 1) * 512, bt1);
        const float4 bb = *(const float4*)(enc_b2 + mt * 16 + lg * 4);
        me[mt][0] = a[0] + bb.x; me[mt][1] = a[1] + bb.y;
        me[mt][2] = a[2] + bb.z; me[mt][3] = a[3] + bb.w;
    }
    // lsd rows (param 72..143) -> ActT cols 0..71 (f16); sls on those lanes
    float slsp = 0.f, qp = 0.f;
    if (lg >= 2) {
        #pragma unroll
        for (int r = 0; r < 4; ++r) slsp += me[4][r];
        *(half4*)&ActT[bt + lg * 4 - 8] = pk4(me[4]);
    }
    #pragma unroll
    for (int mt = 5; mt < 9; ++mt) {
        #pragma unroll
        for (int r = 0; r < 4; ++r) slsp += me[mt][r];
        *(half4*)&ActT[bt + (mt * 16 + lg * 4) - 72] = pk4(me[mt]);
    }
    // q on mean lanes: z = (x - mean) * exp(-lsd)
    #pragma unroll
    for (int mt = 0; mt < 4; ++mt) {
        int m0 = mt * 16 + lg * 4;
        half4 xv = *(const half4*)&ActX[bx + m0];
        half4 lv = *(const half4*)&ActT[bt + m0];
        #pragma unroll
        for (int r = 0; r < 4; ++r) {
            float zz = ((float)xv[r] - me[mt][r]) * __expf(-(float)lv[r]);
            qp = fmaf(zz, zz, qp);
        }
    }
    if (lg < 2) {
        int m0 = 64 + lg * 4;
        half4 xv = *(const half4*)&ActX[bx + m0];
        half4 lv = *(const half4*)&ActT[bt + m0];
        #pragma unroll
        for (int r = 0; r < 4; ++r) {
            float zz = ((float)xv[r] - me[4][r]) * __expf(-(float)lv[r]);
            qp = fmaf(zz, zz, qp);
        }
    }

    // ---- reduce across the 4 lane-groups sharing n, and write ----
    qp     += __shfl_xor(qp, 16);     qp     += __shfl_xor(qp, 32);
    slsp   += __shfl_xor(slsp, 16);   slsp   += __shfl_xor(slsp, 32);
    ld_acc += __shfl_xor(ld_acc, 16); ld_acc += __shfl_xor(ld_acc, 32);
    if (lane < 16) {
        float ldsum = 0.f;
        #pragma unroll
        for (int k = 0; k < NBLK; ++k) ldsum += wsLd[k];
        // 0.5 * 72 * log(2*pi) = 66.16357439
        out[bg0 + 16 * w + lane] = -0.5f * qp - slsp - 66.1635744f + ld_acc + ldsum;
    }
}

// ---------------------------------------------------------------------------
extern "C" void kernel_launch(void* const* d_in, const int* in_sizes, int n_in,
                              void* d_out, int out_size, void* d_ws, size_t ws_size,
                              hipStream_t stream) {
    const float* traj     = (const float*)d_in[0];
    const float* start    = (const float*)d_in[1];
    const float* goal     = (const float*)d_in[2];
    const float* lu_lower = (const float*)d_in[3];
    const float* lu_upper = (const float*)d_in[4];
    const float* lu_diag  = (const float*)d_in[5];
    const float* lu_bias  = (const float*)d_in[6];
    const float* cn_W0    = (const float*)d_in[7];
    const float* cn_b0    = (const float*)d_in[8];
    const float* cn_ctxW  = (const float*)d_in[9];
    const float* cn_ctxb  = (const float*)d_in[10];
    const float* cn_l1W   = (const float*)d_in[11];
    const float* cn_l1b   = (const float*)d_in[12];
    const float* cn_l2W   = (const float*)d_in[13];
    const float* cn_l2b   = (const float*)d_in[14];
    const float* cn_Wf    = (const float*)d_in[15];
    const float* cn_bf    = (const float*)d_in[16];
    const float* enc_W1   = (const float*)d_in[17];
    const float* enc_b1   = (const float*)d_in[18];
    const float* enc_W2   = (const float*)d_in[19];
    const float* enc_b2   = (const float*)d_in[20];

    float* outp = (float*)d_out;
    const int B = in_sizes[0] / DD;

    float*     wsLd = (float*)d_ws;                           // 16 f32
    _Float16*  AR   = (_Float16*)((char*)d_ws + 256);         // 609280 f16

    hipLaunchKernelGGL(prep_lu, dim3(NBLK), dim3(256), 0, stream,
                       lu_lower, lu_upper, lu_diag, AR, wsLd);
    hipLaunchKernelGGL(prep_w, dim3((950 * 64 + 255) / 256), dim3(256), 0, stream,
                       cn_W0, cn_ctxW, cn_l1W, cn_l2W, cn_Wf, enc_W1, enc_W2, AR);

    hipLaunchKernelGGL(flow_kernel, dim3(B / 64), dim3(256), 0, stream,
                       traj, start, goal, lu_bias,
                       cn_b0, cn_ctxb, cn_l1b, cn_l2b, cn_bf,
                       enc_b1, enc_b2, AR, wsLd, outp, B);
}

// Round 8
// 388.469 us; speedup vs baseline: 18.5296x; 1.1670x over previous
//
#include <hip/hip_runtime.h>
#include <math.h>

#define DD   72
#define MID  36
#define NBLK 16

typedef _Float16 half8 __attribute__((ext_vector_type(8)));
typedef _Float16 half4 __attribute__((ext_vector_type(4)));
typedef float    f32x4 __attribute__((ext_vector_type(4)));

// ---- A-fragment arena layout (f16 units). Each frag = 64 lanes x 8 f16 = 512.
// Bias columns are folded into existing zero K-slots (no extra frags):
//   step1 k=72 -> lu_bias ; step2 k=44 -> b0 ; gate k=44 -> cb ; encW1 k=44 -> enc_b1
#define PB    37376            // per-block total
#define S1O   0                // step1 LU matmul: 5 mtiles x 3 ktiles = 15 frags
#define S2O   7680             // step2 W0: 4 x 2 = 8 frags
#define RBO   11776            // resblocks: per i (0/1) stride 10240
#define RB_L1 0                //   l1: 8 frags
#define RB_L2 4096             //   l2: 8 frags
#define RB_GW 8192             //   gate: 4 frags (ktile1 only)
#define S4O   32256            // step4 Wf: 5 x 2 = 10 frags
#define E1O   (16 * PB)        // enc W1: 4 frags
#define E2O   (E1O + 2048)     // enc W2: 9 x 2 = 18 frags
#define AR_TOTAL (E2O + 18 * 512)   // 609280 f16 = 1218560 B

__device__ inline half4 pk4(f32x4 v) {
    half4 h; h[0] = (_Float16)v[0]; h[1] = (_Float16)v[1];
    h[2] = (_Float16)v[2]; h[3] = (_Float16)v[3]; return h;
}
__device__ inline half4 pk4r(f32x4 v) {   // relu + pack
    half4 h;
    h[0] = (_Float16)fmaxf(v[0], 0.f); h[1] = (_Float16)fmaxf(v[1], 0.f);
    h[2] = (_Float16)fmaxf(v[2], 0.f); h[3] = (_Float16)fmaxf(v[3], 0.f);
    return h;
}
// fast sigmoid: v_exp + v_add + v_rcp
__device__ inline float sigf(float x) {
    return __fdividef(1.f, 1.f + __expf(-x));
}

// ---------------------------------------------------------------------------
// Prep 1: LU-composed W -> step1 A-frags + lu_bias column (k=72).
// 80 wgs = (blk, mtile): 5x more CUs than round 7's 16, hoisted inner loop.
// ---------------------------------------------------------------------------
__global__ __launch_bounds__(256) void prep_lu(
    const float* __restrict__ lu_lower,
    const float* __restrict__ lu_upper,
    const float* __restrict__ lu_diag,
    const float* __restrict__ lu_bias,
    _Float16* __restrict__ AR, float* __restrict__ wsLd)
{
    const int wg  = blockIdx.x;
    const int blk = wg / 5, mt = wg % 5;
    const int tid = threadIdx.x;
    __shared__ float Ls[DD][DD + 1];   // stride 73 dwords (odd) -> conflict-free
    __shared__ float Us[DD][DD + 1];
    __shared__ float diag[DD], ldp[DD];

    const float* L = lu_lower + blk * DD * DD;
    const float* U = lu_upper + blk * DD * DD;
    for (int e = tid; e < DD * DD; e += 256) {
        Ls[e / DD][e % DD] = L[e];
        Us[e / DD][e % DD] = U[e];
    }
    if (tid < DD) {
        float v  = lu_diag[blk * DD + tid];
        float sp = log1pf(expf(v)) + 0.001f;
        diag[tid] = sp; ldp[tid] = logf(sp);
    }
    __syncthreads();
    if (mt == 0 && tid == 0) {
        float s = 0.f;
        for (int i = 0; i < DD; ++i) s += ldp[i];
        wsLd[blk] = s;
    }

    if (tid < 192) {
        const int kt   = tid >> 6, lane = tid & 63;
        const int m    = mt * 16 + (lane & 15);
        const int k0   = kt * 32 + (lane >> 4) * 8;
        float acc[8] = {0.f, 0.f, 0.f, 0.f, 0.f, 0.f, 0.f, 0.f};
        if (m < DD) {
            for (int kk = 0; kk < m; ++kk) {
                const float a = Ls[m][kk];
                #pragma unroll
                for (int j = 0; j < 8; ++j) {
                    const int k = k0 + j;
                    if (k < DD && kk < k) acc[j] = fmaf(a, Us[kk][k], acc[j]);
                }
            }
            #pragma unroll
            for (int j = 0; j < 8; ++j) {
                const int k = k0 + j;
                if (k < DD) {
                    if      (m < k)  acc[j] += Us[m][k];
                    else if (m == k) acc[j] += diag[k];
                    else             acc[j] += Ls[m][k] * diag[k];
                }
            }
        }
        half8 hv;
        #pragma unroll
        for (int j = 0; j < 8; ++j) {
            const int k = k0 + j;
            float v = 0.f;
            if (m < DD) {
                if      (k < DD)  v = acc[j];
                else if (k == DD) v = lu_bias[blk * DD + m];   // bias column k=72
            }
            hv[j] = (_Float16)v;
        }
        *(half8*)(AR + (size_t)blk * PB + S1O + (size_t)(mt * 3 + kt) * 512
                  + (size_t)lane * 8) = hv;
    }
}

// ---------------------------------------------------------------------------
// Prep 2: static weights -> A-frags, with b0/cb/enc_b1 bias columns folded.
// ---------------------------------------------------------------------------
__global__ __launch_bounds__(256) void prep_w(
    const float* __restrict__ cn_W0, const float* __restrict__ cn_ctxW,
    const float* __restrict__ cn_l1W, const float* __restrict__ cn_l2W,
    const float* __restrict__ cn_Wf, const float* __restrict__ enc_W1,
    const float* __restrict__ enc_W2,
    const float* __restrict__ cn_b0, const float* __restrict__ cn_ctxb,
    const float* __restrict__ enc_b1,
    _Float16* __restrict__ AR)
{
    int gid = blockIdx.x * 256 + threadIdx.x;
    int fid = gid >> 6, lane = gid & 63;
    if (fid >= 950) return;
    const int mrow = lane & 15, kcol0 = (lane >> 4) * 8;

    const float* src = nullptr; const float* bias = nullptr;
    size_t dst = 0;
    int m = 0, kbase = 0, rows = 64, kv_lo = 0, kv_hi = 64, sstr = 64, ksub = 0, kbias = -1;

    if (fid < 128) {                    // step2 W0 [64 x 44] + b0 at k=44
        int blk = fid >> 3, f = fid & 7;
        int mt = f >> 1, kt = f & 1;
        src = cn_W0 + (size_t)blk * 64 * 44; sstr = 44;
        dst = (size_t)blk * PB + S2O + (size_t)f * 512;
        m = mt * 16 + mrow; kbase = kt * 32 + kcol0; kv_hi = 44;
        bias = cn_b0 + (size_t)blk * 64; kbias = 44;
    } else if (fid < 384) {             // l1 [64 x 64]
        int id = fid - 128, bi = id >> 3, f = id & 7;
        int mt = f >> 1, kt = f & 1;
        src = cn_l1W + (size_t)bi * 4096;
        dst = (size_t)(bi >> 1) * PB + RBO + (size_t)(bi & 1) * 10240 + RB_L1 + (size_t)f * 512;
        m = mt * 16 + mrow; kbase = kt * 32 + kcol0;
    } else if (fid < 640) {             // l2 [64 x 64]
        int id = fid - 384, bi = id >> 3, f = id & 7;
        int mt = f >> 1, kt = f & 1;
        src = cn_l2W + (size_t)bi * 4096;
        dst = (size_t)(bi >> 1) * PB + RBO + (size_t)(bi & 1) * 10240 + RB_L2 + (size_t)f * 512;
        m = mt * 16 + mrow; kbase = kt * 32 + kcol0;
    } else if (fid < 768) {             // gate cW [64 x 8] at k 36..43 + cb at k=44
        int id = fid - 640, bi = id >> 2, mt = id & 3;
        src = cn_ctxW + (size_t)bi * 512; sstr = 8;
        dst = (size_t)(bi >> 1) * PB + RBO + (size_t)(bi & 1) * 10240 + RB_GW + (size_t)mt * 512;
        m = mt * 16 + mrow; kbase = 32 + kcol0; kv_lo = 36; kv_hi = 44; ksub = 36;
        bias = cn_ctxb + (size_t)bi * 64; kbias = 44;
    } else if (fid < 928) {             // step4 Wf [72 x 64]
        int id = fid - 768, blk = id / 10, f = id % 10;
        int mt = f >> 1, kt = f & 1;
        src = cn_Wf + (size_t)blk * 4608;
        dst = (size_t)blk * PB + S4O + (size_t)f * 512;
        m = mt * 16 + mrow; kbase = kt * 32 + kcol0; rows = 72;
    } else if (fid < 932) {             // enc W1 [64 x 8] at k 36..43 + enc_b1 at k=44
        int mt = fid - 928;
        src = enc_W1; sstr = 8;
        dst = E1O + (size_t)mt * 512;
        m = mt * 16 + mrow; kbase = 32 + kcol0; kv_lo = 36; kv_hi = 44; ksub = 36;
        bias = enc_b1; kbias = 44;
    } else {                            // enc W2 [144 x 64]
        int id = fid - 932, mt = id >> 1, kt = id & 1;
        src = enc_W2;
        dst = E2O + (size_t)id * 512;
        m = mt * 16 + mrow; kbase = kt * 32 + kcol0; rows = 144;
    }
    half8 hv;
    #pragma unroll
    for (int j = 0; j < 8; ++j) {
        const int k = kbase + j;
        float v = 0.f;
        if (m < rows) {
            if (k >= kv_lo && k < kv_hi) v = src[(size_t)m * sstr + (k - ksub)];
            else if (k == kbias)         v = bias[m];
        }
        hv[j] = (_Float16)v;
    }
    *(half8*)(AR + dst + (size_t)lane * 8) = hv;
}

// ---------------------------------------------------------------------------
// Flow kernel: 4 waves/wg, each wave owns 16 batch rows. MFMA 16x16x32 f16.
// Biases for step1/step2/gate/encW1 come in via the MFMA (const-1 columns).
// Per-block barrier phase-locks waves for L1 reuse of the A-frag stream.
// ---------------------------------------------------------------------------
#define MFMA_A(acc, off, bf) \
    acc = __builtin_amdgcn_mfma_f32_16x16x32_f16( \
        *(const half8*)(AR + (size_t)(off) + (size_t)lane * 8), bf, acc, 0, 0, 0)

__global__ __launch_bounds__(256, 4) void flow_kernel(
    const float* __restrict__ traj,
    const float* __restrict__ start,
    const float* __restrict__ goal,
    const float* __restrict__ cn_l1b,
    const float* __restrict__ cn_l2b,
    const float* __restrict__ cn_bf,
    const float* __restrict__ enc_b2,
    const _Float16* __restrict__ AR,
    const float* __restrict__ wsLd,
    float* __restrict__ out, int B)
{
    __shared__ __align__(16) _Float16 ActX[64 * 104];  // x(0..71) | 1@72 | 0(73..103)
    __shared__ __align__(16) _Float16 ActH[64 * 72];   // h_id(0..35) | ctx(36..43) | 1@44 | 0
    __shared__ __align__(16) _Float16 ActT[64 * 72];   // hidden scratch

    const int tid  = threadIdx.x;
    const int lane = tid & 63;
    const int w    = __builtin_amdgcn_readfirstlane(tid >> 6);
    const int n    = lane & 15, lg = lane >> 4;
    const int bg0  = blockIdx.x * 64;

    // ---- init: stage x and ctx into LDS ----
    #pragma unroll
    for (int r = 0; r < 9; ++r) {                       // 64*36 float2 = 2304
        int e = tid + 256 * r;
        int b = e / 36, p = e % 36;
        float2 v = *(const float2*)(traj + (size_t)(bg0 + b) * DD + 2 * p);
        ActX[b * 104 + 2 * p]     = (_Float16)v.x;
        ActX[b * 104 + 2 * p + 1] = (_Float16)v.y;
    }
    #pragma unroll
    for (int r = 0; r < 8; ++r) {                       // cols 72..103: 1@72 else 0
        int e = tid + 256 * r;
        int b = e / 32, c = 72 + e % 32;
        ActX[b * 104 + c] = (c == 72) ? (_Float16)1.f : (_Float16)0.f;
    }
    {                                                   // ctx -> ActH cols 36..43
        int b = tid >> 2, cp = tid & 3;
        const float* s = (cp < 2) ? (start + (size_t)(bg0 + b) * 4 + 2 * cp)
                                  : (goal  + (size_t)(bg0 + b) * 4 + 2 * (cp - 2));
        ActH[b * 72 + 36 + 2 * cp]     = (_Float16)s[0];
        ActH[b * 72 + 36 + 2 * cp + 1] = (_Float16)s[1];
    }
    #pragma unroll
    for (int r = 0; r < 7; ++r) {                       // cols 44..71: 1@44 else 0
        int e = tid + 256 * r;
        int b = e / 28, c = 44 + e % 28;
        ActH[b * 72 + c] = (c == 44) ? (_Float16)1.f : (_Float16)0.f;
    }
    __syncthreads();

    const int bx = (16 * w + n) * 104;
    const int bh = (16 * w + n) * 72;
    const int bt = (16 * w + n) * 72;

    float ld_acc = 0.f;
    const f32x4 z4 = {0.f, 0.f, 0.f, 0.f};

    #pragma unroll 1
    for (int blk = 0; blk < NBLK; ++blk) {
        __syncthreads();   // phase-lock the 4 waves -> L1 reuse of A-frag stream
        const size_t B0 = (size_t)blk * PB;

        // ---- step1: y = W @ x + lu_bias (bias via const col 72) ----
        half8 bx0 = *(const half8*)&ActX[bx + 0  + lg * 8];
        half8 bx1 = *(const half8*)&ActX[bx + 32 + lg * 8];
        half8 bx2 = *(const half8*)&ActX[bx + 64 + lg * 8];
        f32x4 y[5];
        #pragma unroll
        for (int mt = 0; mt < 5; ++mt) {
            f32x4 a = z4;
            MFMA_A(a, B0 + S1O + (mt * 3 + 0) * 512, bx0);
            MFMA_A(a, B0 + S1O + (mt * 3 + 1) * 512, bx1);
            MFMA_A(a, B0 + S1O + (mt * 3 + 2) * 512, bx2);
            y[mt] = a;
        }
        // h_id (rows 36..71) -> ActX (in place) and ActH (cols 0..35)
        if (lg >= 1) { half4 hv = pk4(y[2]); int m0 = 32 + lg * 4;
            *(half4*)&ActX[bx + m0] = hv; *(half4*)&ActH[bh + m0 - 36] = hv; }
        {            half4 hv = pk4(y[3]); int m0 = 48 + lg * 4;
            *(half4*)&ActX[bx + m0] = hv; *(half4*)&ActH[bh + m0 - 36] = hv; }
        if (lg < 2) { half4 hv = pk4(y[4]); int m0 = 64 + lg * 4;
            *(half4*)&ActX[bx + m0] = hv; *(half4*)&ActH[bh + m0 - 36] = hv; }

        // ---- step2: t = W0 @ [h_id; ctx] + b0 (bias via const col 44) ----
        half8 bh0 = *(const half8*)&ActH[bh + 0  + lg * 8];
        half8 bh1 = *(const half8*)&ActH[bh + 32 + lg * 8];
        f32x4 t[4];
        #pragma unroll
        for (int mt = 0; mt < 4; ++mt) {
            f32x4 a = z4;
            MFMA_A(a, B0 + S2O + (mt * 2 + 0) * 512, bh0);
            MFMA_A(a, B0 + S2O + (mt * 2 + 1) * 512, bh1);
            t[mt] = a;
        }

        // ---- two residual blocks ----
        #pragma unroll 1
        for (int i = 0; i < 2; ++i) {
            const size_t RB = B0 + RBO + (size_t)i * 10240;
            #pragma unroll
            for (int mt = 0; mt < 4; ++mt)
                *(half4*)&ActT[bt + mt * 16 + lg * 4] = pk4r(t[mt]);   // relu(t)
            half8 bt0 = *(const half8*)&ActT[bt + 0  + lg * 8];
            half8 bt1 = *(const half8*)&ActT[bt + 32 + lg * 8];
            f32x4 a1[4];
            #pragma unroll
            for (int mt = 0; mt < 4; ++mt) {
                f32x4 a = z4;
                MFMA_A(a, RB + RB_L1 + (mt * 2 + 0) * 512, bt0);
                MFMA_A(a, RB + RB_L1 + (mt * 2 + 1) * 512, bt1);
                const float4 bb = *(const float4*)(cn_l1b + (blk * 2 + i) * 64 + mt * 16 + lg * 4);
                a1[mt][0] = a[0] + bb.x; a1[mt][1] = a[1] + bb.y;
                a1[mt][2] = a[2] + bb.z; a1[mt][3] = a[3] + bb.w;
            }
            #pragma unroll
            for (int mt = 0; mt < 4; ++mt)
                *(half4*)&ActT[bt + mt * 16 + lg * 4] = pk4r(a1[mt]);  // relu(a1)
            bt0 = *(const half8*)&ActT[bt + 0  + lg * 8];
            bt1 = *(const half8*)&ActT[bt + 32 + lg * 8];
            #pragma unroll
            for (int mt = 0; mt < 4; ++mt) {
                f32x4 a = z4;
                MFMA_A(a, RB + RB_L2 + (mt * 2 + 0) * 512, bt0);
                MFMA_A(a, RB + RB_L2 + (mt * 2 + 1) * 512, bt1);
                const float4 b2 = *(const float4*)(cn_l2b + (blk * 2 + i) * 64 + mt * 16 + lg * 4);
                f32x4 g = z4;
                MFMA_A(g, RB + RB_GW + mt * 512, bh1);   // cb folded at col 44
                #pragma unroll
                for (int r = 0; r < 4; ++r) {
                    float a2 = a[r] + ((const float*)&b2)[r];
                    float gg = sigf(g[r]);
                    t[mt][r] = fmaf(a2, gg, t[mt][r]);
                }
            }
        }

        // ---- step4: params = Wf @ t + bf ----
        #pragma unroll
        for (int mt = 0; mt < 4; ++mt)
            *(half4*)&ActT[bt + mt * 16 + lg * 4] = pk4(t[mt]);        // raw t
        half8 bt0 = *(const half8*)&ActT[bt + 0  + lg * 8];
        half8 bt1 = *(const half8*)&ActT[bt + 32 + lg * 8];
        f32x4 p[5];
        #pragma unroll
        for (int mt = 0; mt < 5; ++mt) {
            f32x4 a = z4;
            MFMA_A(a, B0 + S4O + (mt * 2 + 0) * 512, bt0);
            MFMA_A(a, B0 + S4O + (mt * 2 + 1) * 512, bt1);
            int bm = mt * 16 + lg * 4; if (bm > 68) bm = 68;   // OOB-safe load (lanes unused)
            const float4 bb = *(const float4*)(cn_bf + blk * DD + bm);
            p[mt][0] = a[0] + bb.x; p[mt][1] = a[1] + bb.y;
            p[mt][2] = a[2] + bb.z; p[mt][3] = a[3] + bb.w;
        }
        // scale rows (param 36..71): sigmoid, logdet, stash to ActT cols 0..35
        if (lg >= 1) {
            f32x4 s;
            #pragma unroll
            for (int r = 0; r < 4; ++r) {
                s[r] = sigf(p[2][r] + 2.f) + 0.001f;
                ld_acc += __logf(s[r]);
            }
            *(half4*)&ActT[bt + (32 + lg * 4) - 36] = pk4(s);
        }
        {
            f32x4 s;
            #pragma unroll
            for (int r = 0; r < 4; ++r) {
                s[r] = sigf(p[3][r] + 2.f) + 0.001f;
                ld_acc += __logf(s[r]);
            }
            *(half4*)&ActT[bt + (48 + lg * 4) - 36] = pk4(s);
        }
        if (lg < 2) {
            f32x4 s;
            #pragma unroll
            for (int r = 0; r < 4; ++r) {
                s[r] = sigf(p[4][r] + 2.f) + 0.001f;
                ld_acc += __logf(s[r]);
            }
            *(half4*)&ActT[bt + (64 + lg * 4) - 36] = pk4(s);
        }
        // combine: x_new[m<36] = y*scale + shift -> ActX
        {
            half4 sv = *(const half4*)&ActT[bt + lg * 4];
            f32x4 xn;
            #pragma unroll
            for (int r = 0; r < 4; ++r) xn[r] = fmaf(y[0][r], (float)sv[r], p[0][r]);
            *(half4*)&ActX[bx + lg * 4] = pk4(xn);
        }
        {
            half4 sv = *(const half4*)&ActT[bt + 16 + lg * 4];
            f32x4 xn;
            #pragma unroll
            for (int r = 0; r < 4; ++r) xn[r] = fmaf(y[1][r], (float)sv[r], p[1][r]);
            *(half4*)&ActX[bx + 16 + lg * 4] = pk4(xn);
        }
        if (lg == 0) {
            half4 sv = *(const half4*)&ActT[bt + 32];
            f32x4 xn;
            #pragma unroll
            for (int r = 0; r < 4; ++r) xn[r] = fmaf(y[2][r], (float)sv[r], p[2][r]);
            *(half4*)&ActX[bx + 32] = pk4(xn);
        }
    }

    // ---- encoder head (enc_b1 folded at col 44) ----
    half8 bh1 = *(const half8*)&ActH[bh + 32 + lg * 8];
    #pragma unroll
    for (int mt = 0; mt < 4; ++mt) {
        f32x4 a = z4;
        MFMA_A(a, E1O + mt * 512, bh1);
        *(half4*)&ActT[bt + mt * 16 + lg * 4] = pk4r(a);               // relu(h)
    }
    half8 bt0 = *(const half8*)&ActT[bt + 0  + lg * 8];
    half8 bt1 = *(const half8*)&ActT[bt + 32 + lg * 8];
    f32x4 me[9];
    #pragma unroll
    for (int mt = 0; mt < 9; ++mt) {
        f32x4 a = z4;
        MFMA_A(a, E2O + (mt * 2 + 0) * 512, bt0);
        MFMA_A(a, E2O + (mt * 2 + 1) * 512, bt1);
        const float4 bb = *(const float4*)(enc_b2 + mt * 16 + lg * 4);
        me[mt][0] = a[0] + bb.x; me[mt][1] = a[1] + bb.y;
        me[mt][2] = a[2] + bb.z; me[mt][3] = a[3] + bb.w;
    }
    // lsd rows (param 72..143) -> ActT cols 0..71 (f16); sls on those lanes
    float slsp = 0.f, qp = 0.f;
    if (lg >= 2) {
        #pragma unroll
        for (int r = 0; r < 4; ++r) slsp += me[4][r];
        *(half4*)&ActT[bt + lg * 4 - 8] = pk4(me[4]);
    }
    #pragma unroll
    for (int mt = 5; mt < 9; ++mt) {
        #pragma unroll
        for (int r = 0; r < 4; ++r) slsp += me[mt][r];
        *(half4*)&ActT[bt + (mt * 16 + lg * 4) - 72] = pk4(me[mt]);
    }
    // q on mean lanes: z = (x - mean) * exp(-lsd)
    #pragma unroll
    for (int mt = 0; mt < 4; ++mt) {
        int m0 = mt * 16 + lg * 4;
        half4 xv = *(const half4*)&ActX[bx + m0];
        half4 lv = *(const half4*)&ActT[bt + m0];
        #pragma unroll
        for (int r = 0; r < 4; ++r) {
            float zz = ((float)xv[r] - me[mt][r]) * __expf(-(float)lv[r]);
            qp = fmaf(zz, zz, qp);
        }
    }
    if (lg < 2) {
        int m0 = 64 + lg * 4;
        half4 xv = *(const half4*)&ActX[bx + m0];
        half4 lv = *(const half4*)&ActT[bt + m0];
        #pragma unroll
        for (int r = 0; r < 4; ++r) {
            float zz = ((float)xv[r] - me[4][r]) * __expf(-(float)lv[r]);
            qp = fmaf(zz, zz, qp);
        }
    }

    // ---- reduce across the 4 lane-groups sharing n, and write ----
    qp     += __shfl_xor(qp, 16);     qp     += __shfl_xor(qp, 32);
    slsp   += __shfl_xor(slsp, 16);   slsp   += __shfl_xor(slsp, 32);
    ld_acc += __shfl_xor(ld_acc, 16); ld_acc += __shfl_xor(ld_acc, 32);
    if (lane < 16) {
        float ldsum = 0.f;
        #pragma unroll
        for (int k = 0; k < NBLK; ++k) ldsum += wsLd[k];
        // 0.5 * 72 * log(2*pi) = 66.16357439
        out[bg0 + 16 * w + lane] = -0.5f * qp - slsp - 66.1635744f + ld_acc + ldsum;
    }
}

// ---------------------------------------------------------------------------
extern "C" void kernel_launch(void* const* d_in, const int* in_sizes, int n_in,
                              void* d_out, int out_size, void* d_ws, size_t ws_size,
                              hipStream_t stream) {
    const float* traj     = (const float*)d_in[0];
    const float* start    = (const float*)d_in[1];
    const float* goal     = (const float*)d_in[2];
    const float* lu_lower = (const float*)d_in[3];
    const float* lu_upper = (const float*)d_in[4];
    const float* lu_diag  = (const float*)d_in[5];
    const float* lu_bias  = (const float*)d_in[6];
    const float* cn_W0    = (const float*)d_in[7];
    const float* cn_b0    = (const float*)d_in[8];
    const float* cn_ctxW  = (const float*)d_in[9];
    const float* cn_ctxb  = (const float*)d_in[10];
    const float* cn_l1W   = (const float*)d_in[11];
    const float* cn_l1b   = (const float*)d_in[12];
    const float* cn_l2W   = (const float*)d_in[13];
    const float* cn_l2b   = (const float*)d_in[14];
    const float* cn_Wf    = (const float*)d_in[15];
    const float* cn_bf    = (const float*)d_in[16];
    const float* enc_W1   = (const float*)d_in[17];
    const float* enc_b1   = (const float*)d_in[18];
    const float* enc_W2   = (const float*)d_in[19];
    const float* enc_b2   = (const float*)d_in[20];

    float* outp = (float*)d_out;
    const int B = in_sizes[0] / DD;

    float*     wsLd = (float*)d_ws;                           // 16 f32
    _Float16*  AR   = (_Float16*)((char*)d_ws + 256);         // 609280 f16

    hipLaunchKernelGGL(prep_lu, dim3(NBLK * 5), dim3(256), 0, stream,
                       lu_lower, lu_upper, lu_diag, lu_bias, AR, wsLd);
    hipLaunchKernelGGL(prep_w, dim3((950 * 64 + 255) / 256), dim3(256), 0, stream,
                       cn_W0, cn_ctxW, cn_l1W, cn_l2W, cn_Wf, enc_W1, enc_W2,
                       cn_b0, cn_ctxb, enc_b1, AR);

    hipLaunchKernelGGL(flow_kernel, dim3(B / 64), dim3(256), 0, stream,
                       traj, start, goal,
                       cn_l1b, cn_l2b, cn_bf, enc_b2,
                       AR, wsLd, outp, B);
}

// Round 9
// 354.278 us; speedup vs baseline: 20.3178x; 1.0965x over previous
//
#include <hip/hip_runtime.h>
#include <math.h>

#define DD   72
#define MID  36
#define NBLK 16

typedef _Float16 half8 __attribute__((ext_vector_type(8)));
typedef _Float16 half4 __attribute__((ext_vector_type(4)));
typedef float    f32x4 __attribute__((ext_vector_type(4)));

// ---- A-fragment arena layout (f16 units). Each frag = 64 lanes x 8 f16 = 512.
// Bias columns folded into zero K-slots:
//   step1 k=72 -> lu_bias ; step2 k=44 -> b0 ; gate k=44 -> cb ; encW1 k=44 -> enc_b1
#define PB    37376
#define S1O   0                // 15 frags
#define S2O   7680             // 8 frags
#define RBO   11776            // per i stride 10240: l1 8, l2 8, gate 4
#define RB_L1 0
#define RB_L2 4096
#define RB_GW 8192
#define S4O   32256            // 10 frags
#define E1O   (16 * PB)
#define E2O   (E1O + 2048)

__device__ inline half4 pk4(f32x4 v) {
    half4 h; h[0] = (_Float16)v[0]; h[1] = (_Float16)v[1];
    h[2] = (_Float16)v[2]; h[3] = (_Float16)v[3]; return h;
}
__device__ inline half4 pk4r(f32x4 v) {
    half4 h;
    h[0] = (_Float16)fmaxf(v[0], 0.f); h[1] = (_Float16)fmaxf(v[1], 0.f);
    h[2] = (_Float16)fmaxf(v[2], 0.f); h[3] = (_Float16)fmaxf(v[3], 0.f);
    return h;
}
__device__ inline float sigf(float x) {
    return __fdividef(1.f, 1.f + __expf(-x));
}
__device__ inline f32x4 MF(half8 a, half8 b, f32x4 c) {
    return __builtin_amdgcn_mfma_f32_16x16x32_f16(a, b, c, 0, 0, 0);
}

// ---------------------------------------------------------------------------
// Merged prep: wgs 0..79 = LU compose (blk, mtile); wgs 80.. = static weights.
// ---------------------------------------------------------------------------
__global__ __launch_bounds__(256) void prep_all(
    const float* __restrict__ lu_lower, const float* __restrict__ lu_upper,
    const float* __restrict__ lu_diag,  const float* __restrict__ lu_bias,
    const float* __restrict__ cn_W0, const float* __restrict__ cn_ctxW,
    const float* __restrict__ cn_l1W, const float* __restrict__ cn_l2W,
    const float* __restrict__ cn_Wf, const float* __restrict__ enc_W1,
    const float* __restrict__ enc_W2,
    const float* __restrict__ cn_b0, const float* __restrict__ cn_ctxb,
    const float* __restrict__ enc_b1,
    _Float16* __restrict__ AR, float* __restrict__ wsLd)
{
    const int tid = threadIdx.x;
    __shared__ float Ls[DD][DD + 1];
    __shared__ float Us[DD][DD + 1];
    __shared__ float diag[DD], ldp[DD];

    if (blockIdx.x < 80) {
        const int wg  = blockIdx.x;
        const int blk = wg / 5, mt = wg % 5;
        const float* L = lu_lower + blk * DD * DD;
        const float* U = lu_upper + blk * DD * DD;
        for (int e = tid; e < DD * DD; e += 256) {
            Ls[e / DD][e % DD] = L[e];
            Us[e / DD][e % DD] = U[e];
        }
        if (tid < DD) {
            float v  = lu_diag[blk * DD + tid];
            float sp = log1pf(expf(v)) + 0.001f;
            diag[tid] = sp; ldp[tid] = logf(sp);
        }
        __syncthreads();
        if (mt == 0 && tid == 0) {
            float s = 0.f;
            for (int i = 0; i < DD; ++i) s += ldp[i];
            wsLd[blk] = s;
        }
        if (tid < 192) {
            const int kt = tid >> 6, lane = tid & 63;
            const int m  = mt * 16 + (lane & 15);
            const int k0 = kt * 32 + (lane >> 4) * 8;
            float acc[8] = {0.f,0.f,0.f,0.f,0.f,0.f,0.f,0.f};
            if (m < DD) {
                for (int kk = 0; kk < m; ++kk) {
                    const float a = Ls[m][kk];
                    #pragma unroll
                    for (int j = 0; j < 8; ++j) {
                        const int k = k0 + j;
                        if (k < DD && kk < k) acc[j] = fmaf(a, Us[kk][k], acc[j]);
                    }
                }
                #pragma unroll
                for (int j = 0; j < 8; ++j) {
                    const int k = k0 + j;
                    if (k < DD) {
                        if      (m < k)  acc[j] += Us[m][k];
                        else if (m == k) acc[j] += diag[k];
                        else             acc[j] += Ls[m][k] * diag[k];
                    }
                }
            }
            half8 hv;
            #pragma unroll
            for (int j = 0; j < 8; ++j) {
                const int k = k0 + j;
                float v = 0.f;
                if (m < DD) {
                    if      (k < DD)  v = acc[j];
                    else if (k == DD) v = lu_bias[blk * DD + m];
                }
                hv[j] = (_Float16)v;
            }
            *(half8*)(AR + (size_t)blk * PB + S1O + (size_t)(mt * 3 + kt) * 512
                      + (size_t)lane * 8) = hv;
        }
        return;
    }

    // ---- static-weight branch ----
    int gid = (blockIdx.x - 80) * 256 + tid;
    int fid = gid >> 6, lane = gid & 63;
    if (fid >= 950) return;
    const int mrow = lane & 15, kcol0 = (lane >> 4) * 8;

    const float* src = nullptr; const float* bias = nullptr;
    size_t dst = 0;
    int m = 0, kbase = 0, rows = 64, kv_lo = 0, kv_hi = 64, sstr = 64, ksub = 0, kbias = -1;

    if (fid < 128) {
        int blk = fid >> 3, f = fid & 7;
        int mt = f >> 1, kt = f & 1;
        src = cn_W0 + (size_t)blk * 64 * 44; sstr = 44;
        dst = (size_t)blk * PB + S2O + (size_t)f * 512;
        m = mt * 16 + mrow; kbase = kt * 32 + kcol0; kv_hi = 44;
        bias = cn_b0 + (size_t)blk * 64; kbias = 44;
    } else if (fid < 384) {
        int id = fid - 128, bi = id >> 3, f = id & 7;
        int mt = f >> 1, kt = f & 1;
        src = cn_l1W + (size_t)bi * 4096;
        dst = (size_t)(bi >> 1) * PB + RBO + (size_t)(bi & 1) * 10240 + RB_L1 + (size_t)f * 512;
        m = mt * 16 + mrow; kbase = kt * 32 + kcol0;
    } else if (fid < 640) {
        int id = fid - 384, bi = id >> 3, f = id & 7;
        int mt = f >> 1, kt = f & 1;
        src = cn_l2W + (size_t)bi * 4096;
        dst = (size_t)(bi >> 1) * PB + RBO + (size_t)(bi & 1) * 10240 + RB_L2 + (size_t)f * 512;
        m = mt * 16 + mrow; kbase = kt * 32 + kcol0;
    } else if (fid < 768) {
        int id = fid - 640, bi = id >> 2, mt = id & 3;
        src = cn_ctxW + (size_t)bi * 512; sstr = 8;
        dst = (size_t)(bi >> 1) * PB + RBO + (size_t)(bi & 1) * 10240 + RB_GW + (size_t)mt * 512;
        m = mt * 16 + mrow; kbase = 32 + kcol0; kv_lo = 36; kv_hi = 44; ksub = 36;
        bias = cn_ctxb + (size_t)bi * 64; kbias = 44;
    } else if (fid < 928) {
        int id = fid - 768, blk = id / 10, f = id % 10;
        int mt = f >> 1, kt = f & 1;
        src = cn_Wf + (size_t)blk * 4608;
        dst = (size_t)blk * PB + S4O + (size_t)f * 512;
        m = mt * 16 + mrow; kbase = kt * 32 + kcol0; rows = 72;
    } else if (fid < 932) {
        int mt = fid - 928;
        src = enc_W1; sstr = 8;
        dst = E1O + (size_t)mt * 512;
        m = mt * 16 + mrow; kbase = 32 + kcol0; kv_lo = 36; kv_hi = 44; ksub = 36;
        bias = enc_b1; kbias = 44;
    } else {
        int id = fid - 932, mt = id >> 1, kt = id & 1;
        src = enc_W2;
        dst = E2O + (size_t)id * 512;
        m = mt * 16 + mrow; kbase = kt * 32 + kcol0; rows = 144;
    }
    half8 hv;
    #pragma unroll
    for (int j = 0; j < 8; ++j) {
        const int k = kbase + j;
        float v = 0.f;
        if (m < rows) {
            if (k >= kv_lo && k < kv_hi) v = src[(size_t)m * sstr + (k - ksub)];
            else if (k == kbias)         v = bias[m];
        }
        hv[j] = (_Float16)v;
    }
    *(half8*)(AR + dst + (size_t)lane * 8) = hv;
}

// ---------------------------------------------------------------------------
// Flow kernel: per-phase register-batched A-frag loads + cross-block prefetch.
// ---------------------------------------------------------------------------
#define LDH8(off) (*(const half8*)(AR + (size_t)(off) + lane8))
#define MFMA_A(acc, off, bf) acc = MF(LDH8(off), bf, acc)

__global__ __launch_bounds__(256, 4) void flow_kernel(
    const float* __restrict__ traj,
    const float* __restrict__ start,
    const float* __restrict__ goal,
    const float* __restrict__ cn_l1b,
    const float* __restrict__ cn_l2b,
    const float* __restrict__ cn_bf,
    const float* __restrict__ enc_b2,
    const _Float16* __restrict__ AR,
    const float* __restrict__ wsLd,
    float* __restrict__ out, int B)
{
    __shared__ __align__(16) _Float16 ActX[64 * 104];  // x(0..71) | 1@72 | 0
    __shared__ __align__(16) _Float16 ActH[64 * 72];   // h_id | ctx(36..43) | 1@44 | 0
    __shared__ __align__(16) _Float16 ActT[64 * 72];

    const int tid  = threadIdx.x;
    const int lane = tid & 63;
    const int w    = __builtin_amdgcn_readfirstlane(tid >> 6);
    const int n    = lane & 15, lg = lane >> 4;
    const int bg0  = blockIdx.x * 64;
    const size_t lane8 = (size_t)lane * 8;

    // ---- init: stage x and ctx into LDS ----
    #pragma unroll
    for (int r = 0; r < 9; ++r) {
        int e = tid + 256 * r;
        int b = e / 36, p = e % 36;
        float2 v = *(const float2*)(traj + (size_t)(bg0 + b) * DD + 2 * p);
        ActX[b * 104 + 2 * p]     = (_Float16)v.x;
        ActX[b * 104 + 2 * p + 1] = (_Float16)v.y;
    }
    #pragma unroll
    for (int r = 0; r < 8; ++r) {
        int e = tid + 256 * r;
        int b = e / 32, c = 72 + e % 32;
        ActX[b * 104 + c] = (c == 72) ? (_Float16)1.f : (_Float16)0.f;
    }
    {
        int b = tid >> 2, cp = tid & 3;
        const float* s = (cp < 2) ? (start + (size_t)(bg0 + b) * 4 + 2 * cp)
                                  : (goal  + (size_t)(bg0 + b) * 4 + 2 * (cp - 2));
        ActH[b * 72 + 36 + 2 * cp]     = (_Float16)s[0];
        ActH[b * 72 + 36 + 2 * cp + 1] = (_Float16)s[1];
    }
    #pragma unroll
    for (int r = 0; r < 7; ++r) {
        int e = tid + 256 * r;
        int b = e / 28, c = 44 + e % 28;
        ActH[b * 72 + c] = (c == 44) ? (_Float16)1.f : (_Float16)0.f;
    }

    // prologue prefetch: block 0 step1 frags for mtiles 0,1
    half8 s1p0 = LDH8(S1O + 0 * 512), s1p1 = LDH8(S1O + 1 * 512),
          s1p2 = LDH8(S1O + 2 * 512), s1p3 = LDH8(S1O + 3 * 512),
          s1p4 = LDH8(S1O + 4 * 512), s1p5 = LDH8(S1O + 5 * 512);

    __syncthreads();

    const int bx = (16 * w + n) * 104;
    const int bh = (16 * w + n) * 72;
    const int bt = (16 * w + n) * 72;

    float ld_acc = 0.f;
    const f32x4 z4 = {0.f, 0.f, 0.f, 0.f};

    #pragma unroll 1
    for (int blk = 0; blk < NBLK; ++blk) {
        __syncthreads();   // phase-lock waves (per-phase L1 reuse)
        const size_t B0 = (size_t)blk * PB;

        // ---- step1: batch remaining 9 frag loads, then compute ----
        half8 f6  = LDH8(B0 + S1O + 6 * 512),  f7  = LDH8(B0 + S1O + 7 * 512),
              f8  = LDH8(B0 + S1O + 8 * 512),  f9  = LDH8(B0 + S1O + 9 * 512),
              f10 = LDH8(B0 + S1O + 10 * 512), f11 = LDH8(B0 + S1O + 11 * 512),
              f12 = LDH8(B0 + S1O + 12 * 512), f13 = LDH8(B0 + S1O + 13 * 512),
              f14 = LDH8(B0 + S1O + 14 * 512);
        half8 bx0 = *(const half8*)&ActX[bx + 0  + lg * 8];
        half8 bx1 = *(const half8*)&ActX[bx + 32 + lg * 8];
        half8 bx2 = *(const half8*)&ActX[bx + 64 + lg * 8];
        f32x4 y[5];
        y[0] = MF(s1p2, bx2, MF(s1p1, bx1, MF(s1p0, bx0, z4)));
        y[1] = MF(s1p5, bx2, MF(s1p4, bx1, MF(s1p3, bx0, z4)));
        y[2] = MF(f8,  bx2, MF(f7,  bx1, MF(f6,  bx0, z4)));
        y[3] = MF(f11, bx2, MF(f10, bx1, MF(f9,  bx0, z4)));
        y[4] = MF(f14, bx2, MF(f13, bx1, MF(f12, bx0, z4)));

        // ---- step2: issue W0 loads, then h_id LDS round-trip, then MFMAs ----
        half8 g0 = LDH8(B0 + S2O + 0 * 512), g1 = LDH8(B0 + S2O + 1 * 512),
              g2 = LDH8(B0 + S2O + 2 * 512), g3 = LDH8(B0 + S2O + 3 * 512),
              g4 = LDH8(B0 + S2O + 4 * 512), g5 = LDH8(B0 + S2O + 5 * 512),
              g6 = LDH8(B0 + S2O + 6 * 512), g7 = LDH8(B0 + S2O + 7 * 512);
        if (lg >= 1) { half4 hv = pk4(y[2]); int m0 = 32 + lg * 4;
            *(half4*)&ActX[bx + m0] = hv; *(half4*)&ActH[bh + m0 - 36] = hv; }
        {            half4 hv = pk4(y[3]); int m0 = 48 + lg * 4;
            *(half4*)&ActX[bx + m0] = hv; *(half4*)&ActH[bh + m0 - 36] = hv; }
        if (lg < 2) { half4 hv = pk4(y[4]); int m0 = 64 + lg * 4;
            *(half4*)&ActX[bx + m0] = hv; *(half4*)&ActH[bh + m0 - 36] = hv; }
        half8 bh0 = *(const half8*)&ActH[bh + 0  + lg * 8];
        half8 bh1 = *(const half8*)&ActH[bh + 32 + lg * 8];
        f32x4 t[4];
        t[0] = MF(g1, bh1, MF(g0, bh0, z4));
        t[1] = MF(g3, bh1, MF(g2, bh0, z4));
        t[2] = MF(g5, bh1, MF(g4, bh0, z4));
        t[3] = MF(g7, bh1, MF(g6, bh0, z4));

        // ---- two residual blocks (unrolled) ----
        #pragma unroll
        for (int i = 0; i < 2; ++i) {
            const size_t RB = B0 + RBO + (size_t)i * 10240;
            half8 r0 = LDH8(RB + RB_L1 + 0 * 512), r1 = LDH8(RB + RB_L1 + 1 * 512),
                  r2 = LDH8(RB + RB_L1 + 2 * 512), r3 = LDH8(RB + RB_L1 + 3 * 512),
                  r4 = LDH8(RB + RB_L1 + 4 * 512), r5 = LDH8(RB + RB_L1 + 5 * 512),
                  r6 = LDH8(RB + RB_L1 + 6 * 512), r7 = LDH8(RB + RB_L1 + 7 * 512);
            #pragma unroll
            for (int mt = 0; mt < 4; ++mt)
                *(half4*)&ActT[bt + mt * 16 + lg * 4] = pk4r(t[mt]);
            half8 bt0 = *(const half8*)&ActT[bt + 0  + lg * 8];
            half8 bt1 = *(const half8*)&ActT[bt + 32 + lg * 8];
            f32x4 a1[4];
            a1[0] = MF(r1, bt1, MF(r0, bt0, z4));
            a1[1] = MF(r3, bt1, MF(r2, bt0, z4));
            a1[2] = MF(r5, bt1, MF(r4, bt0, z4));
            a1[3] = MF(r7, bt1, MF(r6, bt0, z4));
            half8 q0 = LDH8(RB + RB_L2 + 0 * 512), q1 = LDH8(RB + RB_L2 + 1 * 512),
                  q2 = LDH8(RB + RB_L2 + 2 * 512), q3 = LDH8(RB + RB_L2 + 3 * 512),
                  q4 = LDH8(RB + RB_L2 + 4 * 512), q5 = LDH8(RB + RB_L2 + 5 * 512),
                  q6 = LDH8(RB + RB_L2 + 6 * 512), q7 = LDH8(RB + RB_L2 + 7 * 512);
            half8 w0 = LDH8(RB + RB_GW + 0 * 512), w1 = LDH8(RB + RB_GW + 1 * 512),
                  w2 = LDH8(RB + RB_GW + 2 * 512), w3 = LDH8(RB + RB_GW + 3 * 512);
            #pragma unroll
            for (int mt = 0; mt < 4; ++mt) {
                const float4 bb = *(const float4*)(cn_l1b + (blk * 2 + i) * 64 + mt * 16 + lg * 4);
                a1[mt][0] += bb.x; a1[mt][1] += bb.y; a1[mt][2] += bb.z; a1[mt][3] += bb.w;
                *(half4*)&ActT[bt + mt * 16 + lg * 4] = pk4r(a1[mt]);
            }
            bt0 = *(const half8*)&ActT[bt + 0  + lg * 8];
            bt1 = *(const half8*)&ActT[bt + 32 + lg * 8];
            f32x4 a2[4], gg[4];
            a2[0] = MF(q1, bt1, MF(q0, bt0, z4));
            a2[1] = MF(q3, bt1, MF(q2, bt0, z4));
            a2[2] = MF(q5, bt1, MF(q4, bt0, z4));
            a2[3] = MF(q7, bt1, MF(q6, bt0, z4));
            gg[0] = MF(w0, bh1, z4); gg[1] = MF(w1, bh1, z4);
            gg[2] = MF(w2, bh1, z4); gg[3] = MF(w3, bh1, z4);
            #pragma unroll
            for (int mt = 0; mt < 4; ++mt) {
                const float4 b2 = *(const float4*)(cn_l2b + (blk * 2 + i) * 64 + mt * 16 + lg * 4);
                #pragma unroll
                for (int r = 0; r < 4; ++r) {
                    float av = a2[mt][r] + ((const float*)&b2)[r];
                    t[mt][r] = fmaf(av, sigf(gg[mt][r]), t[mt][r]);
                }
            }
        }

        // ---- step4: batch Wf loads, LDS round-trip, MFMAs ----
        half8 h0 = LDH8(B0 + S4O + 0 * 512), h1 = LDH8(B0 + S4O + 1 * 512),
              h2 = LDH8(B0 + S4O + 2 * 512), h3 = LDH8(B0 + S4O + 3 * 512),
              h4 = LDH8(B0 + S4O + 4 * 512), h5 = LDH8(B0 + S4O + 5 * 512),
              h6 = LDH8(B0 + S4O + 6 * 512), h7 = LDH8(B0 + S4O + 7 * 512),
              h8 = LDH8(B0 + S4O + 8 * 512), h9 = LDH8(B0 + S4O + 9 * 512);
        #pragma unroll
        for (int mt = 0; mt < 4; ++mt)
            *(half4*)&ActT[bt + mt * 16 + lg * 4] = pk4(t[mt]);
        half8 bt0 = *(const half8*)&ActT[bt + 0  + lg * 8];
        half8 bt1 = *(const half8*)&ActT[bt + 32 + lg * 8];
        f32x4 p[5];
        p[0] = MF(h1, bt1, MF(h0, bt0, z4));
        p[1] = MF(h3, bt1, MF(h2, bt0, z4));
        p[2] = MF(h5, bt1, MF(h4, bt0, z4));
        p[3] = MF(h7, bt1, MF(h6, bt0, z4));
        p[4] = MF(h9, bt1, MF(h8, bt0, z4));
        #pragma unroll
        for (int mt = 0; mt < 5; ++mt) {
            int bm = mt * 16 + lg * 4; if (bm > 68) bm = 68;
            const float4 bb = *(const float4*)(cn_bf + blk * DD + bm);
            p[mt][0] += bb.x; p[mt][1] += bb.y; p[mt][2] += bb.z; p[mt][3] += bb.w;
        }

        // ---- cross-block prefetch: next block's step1 mtiles 0,1 ----
        {
            const size_t Bn = (size_t)(blk < NBLK - 1 ? blk + 1 : blk) * PB;
            s1p0 = LDH8(Bn + S1O + 0 * 512); s1p1 = LDH8(Bn + S1O + 1 * 512);
            s1p2 = LDH8(Bn + S1O + 2 * 512); s1p3 = LDH8(Bn + S1O + 3 * 512);
            s1p4 = LDH8(Bn + S1O + 4 * 512); s1p5 = LDH8(Bn + S1O + 5 * 512);
        }

        // ---- scale rows: sigmoid + logdet; stash to ActT cols 0..35 ----
        if (lg >= 1) {
            f32x4 s;
            #pragma unroll
            for (int r = 0; r < 4; ++r) {
                s[r] = sigf(p[2][r] + 2.f) + 0.001f;
                ld_acc += __logf(s[r]);
            }
            *(half4*)&ActT[bt + (32 + lg * 4) - 36] = pk4(s);
        }
        {
            f32x4 s;
            #pragma unroll
            for (int r = 0; r < 4; ++r) {
                s[r] = sigf(p[3][r] + 2.f) + 0.001f;
                ld_acc += __logf(s[r]);
            }
            *(half4*)&ActT[bt + (48 + lg * 4) - 36] = pk4(s);
        }
        if (lg < 2) {
            f32x4 s;
            #pragma unroll
            for (int r = 0; r < 4; ++r) {
                s[r] = sigf(p[4][r] + 2.f) + 0.001f;
                ld_acc += __logf(s[r]);
            }
            *(half4*)&ActT[bt + (64 + lg * 4) - 36] = pk4(s);
        }
        // ---- combine: x_new[m<36] = y*scale + shift -> ActX ----
        {
            half4 sv = *(const half4*)&ActT[bt + lg * 4];
            f32x4 xn;
            #pragma unroll
            for (int r = 0; r < 4; ++r) xn[r] = fmaf(y[0][r], (float)sv[r], p[0][r]);
            *(half4*)&ActX[bx + lg * 4] = pk4(xn);
        }
        {
            half4 sv = *(const half4*)&ActT[bt + 16 + lg * 4];
            f32x4 xn;
            #pragma unroll
            for (int r = 0; r < 4; ++r) xn[r] = fmaf(y[1][r], (float)sv[r], p[1][r]);
            *(half4*)&ActX[bx + 16 + lg * 4] = pk4(xn);
        }
        if (lg == 0) {
            half4 sv = *(const half4*)&ActT[bt + 32];
            f32x4 xn;
            #pragma unroll
            for (int r = 0; r < 4; ++r) xn[r] = fmaf(y[2][r], (float)sv[r], p[2][r]);
            *(half4*)&ActX[bx + 32] = pk4(xn);
        }
    }

    // ---- encoder head (once; keep embedded loads) ----
    half8 bh1 = *(const half8*)&ActH[bh + 32 + lg * 8];
    #pragma unroll
    for (int mt = 0; mt < 4; ++mt) {
        f32x4 a = z4;
        MFMA_A(a, E1O + mt * 512, bh1);
        *(half4*)&ActT[bt + mt * 16 + lg * 4] = pk4r(a);
    }
    half8 bt0 = *(const half8*)&ActT[bt + 0  + lg * 8];
    half8 bt1 = *(const half8*)&ActT[bt + 32 + lg * 8];
    f32x4 me[9];
    #pragma unroll
    for (int mt = 0; mt < 9; ++mt) {
        f32x4 a = z4;
        MFMA_A(a, E2O + (mt * 2 + 0) * 512, bt0);
        MFMA_A(a, E2O + (mt * 2 + 1) * 512, bt1);
        const float4 bb = *(const float4*)(enc_b2 + mt * 16 + lg * 4);
        me[mt][0] = a[0] + bb.x; me[mt][1] = a[1] + bb.y;
        me[mt][2] = a[2] + bb.z; me[mt][3] = a[3] + bb.w;
    }
    float slsp = 0.f, qp = 0.f;
    if (lg >= 2) {
        #pragma unroll
        for (int r = 0; r < 4; ++r) slsp += me[4][r];
        *(half4*)&ActT[bt + lg * 4 - 8] = pk4(me[4]);
    }
    #pragma unroll
    for (int mt = 5; mt < 9; ++mt) {
        #pragma unroll
        for (int r = 0; r < 4; ++r) slsp += me[mt][r];
        *(half4*)&ActT[bt + (mt * 16 + lg * 4) - 72] = pk4(me[mt]);
    }
    #pragma unroll
    for (int mt = 0; mt < 4; ++mt) {
        int m0 = mt * 16 + lg * 4;
        half4 xv = *(const half4*)&ActX[bx + m0];
        half4 lv = *(const half4*)&ActT[bt + m0];
        #pragma unroll
        for (int r = 0; r < 4; ++r) {
            float zz = ((float)xv[r] - me[mt][r]) * __expf(-(float)lv[r]);
            qp = fmaf(zz, zz, qp);
        }
    }
    if (lg < 2) {
        int m0 = 64 + lg * 4;
        half4 xv = *(const half4*)&ActX[bx + m0];
        half4 lv = *(const half4*)&ActT[bt + m0];
        #pragma unroll
        for (int r = 0; r < 4; ++r) {
            float zz = ((float)xv[r] - me[4][r]) * __expf(-(float)lv[r]);
            qp = fmaf(zz, zz, qp);
        }
    }

    qp     += __shfl_xor(qp, 16);     qp     += __shfl_xor(qp, 32);
    slsp   += __shfl_xor(slsp, 16);   slsp   += __shfl_xor(slsp, 32);
    ld_acc += __shfl_xor(ld_acc, 16); ld_acc += __shfl_xor(ld_acc, 32);
    if (lane < 16) {
        float ldsum = 0.f;
        #pragma unroll
        for (int k = 0; k < NBLK; ++k) ldsum += wsLd[k];
        out[bg0 + 16 * w + lane] = -0.5f * qp - slsp - 66.1635744f + ld_acc + ldsum;
    }
}

// ---------------------------------------------------------------------------
extern "C" void kernel_launch(void* const* d_in, const int* in_sizes, int n_in,
                              void* d_out, int out_size, void* d_ws, size_t ws_size,
                              hipStream_t stream) {
    const float* traj     = (const float*)d_in[0];
    const float* start    = (const float*)d_in[1];
    const float* goal     = (const float*)d_in[2];
    const float* lu_lower = (const float*)d_in[3];
    const float* lu_upper = (const float*)d_in[4];
    const float* lu_diag  = (const float*)d_in[5];
    const float* lu_bias  = (const float*)d_in[6];
    const float* cn_W0    = (const float*)d_in[7];
    const float* cn_b0    = (const float*)d_in[8];
    const float* cn_ctxW  = (const float*)d_in[9];
    const float* cn_ctxb  = (const float*)d_in[10];
    const float* cn_l1W   = (const float*)d_in[11];
    const float* cn_l1b   = (const float*)d_in[12];
    const float* cn_l2W   = (const float*)d_in[13];
    const float* cn_l2b   = (const float*)d_in[14];
    const float* cn_Wf    = (const float*)d_in[15];
    const float* cn_bf    = (const float*)d_in[16];
    const float* enc_W1   = (const float*)d_in[17];
    const float* enc_b1   = (const float*)d_in[18];
    const float* enc_W2   = (const float*)d_in[19];
    const float* enc_b2   = (const float*)d_in[20];

    float* outp = (float*)d_out;
    const int B = in_sizes[0] / DD;

    float*     wsLd = (float*)d_ws;
    _Float16*  AR   = (_Float16*)((char*)d_ws + 256);

    // wgs 0..79: LU compose; wgs 80..317: static weights (950 frags)
    hipLaunchKernelGGL(prep_all, dim3(80 + 238), dim3(256), 0, stream,
                       lu_lower, lu_upper, lu_diag, lu_bias,
                       cn_W0, cn_ctxW, cn_l1W, cn_l2W, cn_Wf, enc_W1, enc_W2,
                       cn_b0, cn_ctxb, enc_b1, AR, wsLd);

    hipLaunchKernelGGL(flow_kernel, dim3(B / 64), dim3(256), 0, stream,
                       traj, start, goal,
                       cn_l1b, cn_l2b, cn_bf, enc_b2,
                       AR, wsLd, outp, B);
}